// Round 1
// baseline (10441.202 us; speedup 1.0000x reference)
//
#include <hip/hip_runtime.h>
#include <hip/hip_bf16.h>
#include <math.h>

// Problem constants
constexpr int Bz  = 32;
constexpr int S   = 197;
constexpr int E   = 256;
constexpr int Hn  = 16;
constexpr int HD  = 16;
constexpr int Fd  = 3072;
constexpr int Ln  = 12;
constexpr int MS  = Bz * S;         // 6304 tokens
constexpr int DVL = 50, DVR = 49, DVT = 49;

// ---------------------------------------------------------------------------
// block-wide reduce (256 threads). op: 0=sum, 1=max. Returns value to all.
__device__ __forceinline__ float block_reduce(float v, float* red, int op) {
    int e = threadIdx.x;
    red[e] = v;
    __syncthreads();
    for (int s2 = 128; s2 > 0; s2 >>= 1) {
        if (e < s2) red[e] = op ? fmaxf(red[e], red[e + s2]) : red[e] + red[e + s2];
        __syncthreads();
    }
    float r = red[0];
    __syncthreads();
    return r;
}

// ---------------------------------------------------------------------------
// Patch embedding + cls token + pos emb. One block per token (B*S blocks).
__global__ __launch_bounds__(256) void patch_embed_kernel(
        const float* __restrict__ x, const float* __restrict__ Wp,
        const float* __restrict__ bp, const float* __restrict__ cls,
        const float* __restrict__ pos, float* __restrict__ h) {
    int tok = blockIdx.x;          // 0..MS-1
    int b = tok / S, s = tok % S;
    int e = threadIdx.x;           // 0..255
    if (s == 0) {
        h[(size_t)tok * E + e] = cls[e] + pos[e];
        return;
    }
    __shared__ float patch[256];
    int pi = s - 1;
    int i = pi / 14, j = pi % 14;
    int pr = e / 16, pc = e % 16;
    patch[e] = x[((size_t)(b * 224 + i * 16 + pr)) * 224 + j * 16 + pc];
    __syncthreads();
    float acc = bp[e];
    const float* w = Wp + (size_t)e * 256;
    #pragma unroll 8
    for (int k = 0; k < 256; k++) acc += patch[k] * w[k];
    h[(size_t)tok * E + e] = acc + pos[(size_t)s * E + e];
}

// ---------------------------------------------------------------------------
// One rag branch:
//   a = softmax(((xsrc@Wk.T+bk)@key)*scale) ;  f[fo..fo+dv) = Wv@(a@xsrc)+bv
// Factored: score[s] = (xsrc[s]·u + c)*scale with u = Wk.T@key, c = bk·key.
__device__ void rag_branch(const float* __restrict__ xsrc,
                           const float* __restrict__ Wk, const float* __restrict__ bk,
                           const float* __restrict__ Wv, const float* __restrict__ bv,
                           int dv, const float* __restrict__ key,
                           float* u, float* a, float* f, int fo, float* red) {
    int e = threadIdx.x;
    float uu = 0.f;
    for (int i = 0; i < 256; i++) uu += Wk[(size_t)i * 256 + e] * key[i];
    u[e] = uu;
    float c = block_reduce(bk[e] * key[e], red, 0);   // barrier also publishes u[]
    float sc = -1e30f;
    if (e < S) {
        float v = c;
        const float* row = xsrc + (size_t)e * E;
        for (int k = 0; k < 256; k++) v += row[k] * u[k];
        sc = v * 0.0625f;                              // 1/sqrt(E)
    }
    float mx = block_reduce(sc, red, 1);
    float ex = (e < S) ? expf(sc - mx) : 0.f;
    float denom = block_reduce(ex, red, 0);
    a[e] = ex / denom;
    __syncthreads();
    float xb = 0.f;
    for (int s = 0; s < S; s++) xb += a[s] * xsrc[(size_t)s * E + e];
    __syncthreads();          // everyone done reading u (scores) before overwrite
    u[e] = xb;
    __syncthreads();
    if (e < dv) {
        float r = bv[e];
        const float* wrow = Wv + (size_t)e * E;
        for (int k = 0; k < 256; k++) r += wrow[k] * u[k];
        f[fo + e] = r;
    }
    __syncthreads();
}

// One block per mid sample t=0..29: xl=h0[t], xt=h0[t+1], xr=h0[t+2].
__global__ __launch_bounds__(256) void rag_kernel(
        const float* __restrict__ h0, float* __restrict__ h1,
        const float* __restrict__ Wkl, const float* __restrict__ bkl,
        const float* __restrict__ Wvl, const float* __restrict__ bvl,
        const float* __restrict__ Wkr, const float* __restrict__ bkr,
        const float* __restrict__ Wvr, const float* __restrict__ bvr,
        const float* __restrict__ Wkt, const float* __restrict__ bkt,
        const float* __restrict__ Wvt, const float* __restrict__ bvt) {
    int t = blockIdx.x;
    int e = threadIdx.x;
    const float* xl = h0 + (size_t)t * S * E;
    const float* xt = xl + (size_t)S * E;
    const float* xr = xt + (size_t)S * E;
    __shared__ float rt[256], ml[256], mr[256], u[256], a[256], f[256], red[256];
    float sl = 0.f, st = 0.f, sr = 0.f;
    for (int s = 0; s < S; s++) {
        sl += xl[(size_t)s * E + e];
        st += xt[(size_t)s * E + e];
        sr += xr[(size_t)s * E + e];
    }
    const float invS = 1.f / (float)S;
    rt[e] = st * invS; ml[e] = sl * invS; mr[e] = sr * invS;
    __syncthreads();
    rag_branch(xl, Wkl, bkl, Wvl, bvl, DVL, rt, u, a, f, 0, red);           // rl
    rag_branch(xt, Wkt, bkt, Wvt, bvt, DVT, ml, u, a, f, DVL, red);          // rtl
    rag_branch(xt, Wkt, bkt, Wvt, bvt, DVT, mr, u, a, f, DVL + DVT, red);    // rtr
    rag_branch(xr, Wkr, bkr, Wvr, bvr, DVR, rt, u, a, f, DVL + 2 * DVT, red);// rr
    // mid[s,e] = f[s] * rt[e]
    float rte = rt[e];
    float* outp = h1 + ((size_t)(t + 1) * S) * E;
    for (int s = 0; s < S; s++) outp[(size_t)s * E + e] = f[s] * rte;
}

// copy h0 samples 0 and 31 into h1
__global__ __launch_bounds__(256) void copy_edges(const float* __restrict__ h0,
                                                  float* __restrict__ h1) {
    int i = blockIdx.x * 256 + threadIdx.x;
    int n = S * E;
    if (i < n) h1[i] = h0[i];
    else if (i < 2 * n) {
        int j = i - n;
        size_t o = (size_t)31 * S * E + j;
        h1[o] = h0[o];
    }
}

// ---------------------------------------------------------------------------
// LayerNorm over E=256. One block per token.
__global__ __launch_bounds__(256) void ln_kernel(const float* __restrict__ in,
                                                 float* __restrict__ out,
                                                 const float* __restrict__ g,
                                                 const float* __restrict__ b) {
    __shared__ float red[256];
    int tok = blockIdx.x, e = threadIdx.x;
    float v = in[(size_t)tok * E + e];
    float mean = block_reduce(v, red, 0) * (1.f / 256.f);
    float d = v - mean;
    float var = block_reduce(d * d, red, 0) * (1.f / 256.f);
    out[(size_t)tok * E + e] = d * rsqrtf(var + 1e-5f) * g[e] + b[e];
}

// ---------------------------------------------------------------------------
// C[M,N] (ld ldc) = act( A[M,K](ld lda) @ W[N,K](ld ldw).T + bias )  [+= if RES]
// Tiles 64x64x16, 256 threads, 4x4 per thread. N,K multiples of 16/64; M ragged.
template <int ACT, int RES>
__global__ __launch_bounds__(256) void gemm_kernel(
        const float* __restrict__ A, int lda,
        const float* __restrict__ W, int ldw,
        const float* __restrict__ bias,
        float* __restrict__ C, int ldc, int M, int N, int K) {
    __shared__ float As[16][65];
    __shared__ float Bs[16][65];
    int m0 = blockIdx.y * 64, n0 = blockIdx.x * 64;
    int tid = threadIdx.x;
    int tx = tid % 16, ty = tid / 16;
    int lk = tid % 16, lr = tid / 16;
    float acc[4][4] = {};
    for (int k0 = 0; k0 < K; k0 += 16) {
        #pragma unroll
        for (int r = 0; r < 64; r += 16) {
            int m = m0 + lr + r;
            As[lk][lr + r] = (m < M) ? A[(size_t)m * lda + k0 + lk] : 0.f;
            int n = n0 + lr + r;
            Bs[lk][lr + r] = W[(size_t)n * ldw + k0 + lk];
        }
        __syncthreads();
        #pragma unroll
        for (int k = 0; k < 16; k++) {
            float ar[4], br[4];
            #pragma unroll
            for (int i = 0; i < 4; i++) ar[i] = As[k][ty * 4 + i];
            #pragma unroll
            for (int j = 0; j < 4; j++) br[j] = Bs[k][tx * 4 + j];
            #pragma unroll
            for (int i = 0; i < 4; i++)
                #pragma unroll
                for (int j = 0; j < 4; j++) acc[i][j] += ar[i] * br[j];
        }
        __syncthreads();
    }
    #pragma unroll
    for (int i = 0; i < 4; i++) {
        int m = m0 + ty * 4 + i;
        if (m >= M) break;
        #pragma unroll
        for (int j = 0; j < 4; j++) {
            int n = n0 + tx * 4 + j;
            float v = acc[i][j] + (bias ? bias[n] : 0.f);
            if (ACT == 1) v = 0.5f * v * (1.f + erff(v * 0.70710678118654752f));
            if (RES) C[(size_t)m * ldc + n] += v;
            else     C[(size_t)m * ldc + n] = v;
        }
    }
}

// ---------------------------------------------------------------------------
// Attention: one block per (sample, head). K/V staged in LDS; online softmax.
__global__ __launch_bounds__(256) void attn_kernel(const float* __restrict__ qkv,
                                                   float* __restrict__ o) {
    int bh = blockIdx.x;
    int b = bh / Hn, hh = bh % Hn;
    __shared__ float Ks[S][HD];
    __shared__ float Vs[S][HD];
    int tid = threadIdx.x;
    for (int i = tid; i < S * HD; i += 256) {
        int s = i / HD, d = i % HD;
        size_t base = ((size_t)(b * S + s)) * 768 + hh * HD + d;
        Ks[s][d] = qkv[base + 256];
        Vs[s][d] = qkv[base + 512];
    }
    __syncthreads();
    int s = tid;
    if (s < S) {
        float q[HD];
        const float* qp = qkv + ((size_t)(b * S + s)) * 768 + hh * HD;
        #pragma unroll
        for (int d = 0; d < HD; d++) q[d] = qp[d] * 0.25f;   // 1/sqrt(HD)
        float m = -1e30f, l = 0.f, acc[HD] = {};
        for (int k = 0; k < S; k++) {
            float sc = 0.f;
            #pragma unroll
            for (int d = 0; d < HD; d++) sc += q[d] * Ks[k][d];
            float mn = fmaxf(m, sc);
            float corr = expf(m - mn);
            float p = expf(sc - mn);
            l = l * corr + p;
            #pragma unroll
            for (int d = 0; d < HD; d++) acc[d] = acc[d] * corr + p * Vs[k][d];
            m = mn;
        }
        float inv = 1.f / l;
        float* op = o + ((size_t)(b * S + s)) * E + hh * HD;
        #pragma unroll
        for (int d = 0; d < HD; d++) op[d] = acc[d] * inv;
    }
}

// ---------------------------------------------------------------------------
// Final LN on cls token + head GEMM. One block per sample.
__global__ __launch_bounds__(256) void head_kernel(
        const float* __restrict__ h, const float* __restrict__ g,
        const float* __restrict__ bb, const float* __restrict__ Wh,
        const float* __restrict__ bh, float* __restrict__ out) {
    __shared__ float red[256];
    __shared__ float xs[256];
    int b = blockIdx.x, e = threadIdx.x;
    float v = h[((size_t)(b * S)) * E + e];
    float mean = block_reduce(v, red, 0) * (1.f / 256.f);
    float d = v - mean;
    float var = block_reduce(d * d, red, 0) * (1.f / 256.f);
    float xn = d * rsqrtf(var + 1e-5f) * g[e] + bb[e];
    xs[e] = xn;
    __syncthreads();
    for (int n = 0; n < 8; n++) {
        float s = block_reduce(xs[e] * Wh[(size_t)n * 256 + e], red, 0);
        if (e == 0) out[b * 8 + n] = s + bh[n];
    }
}

// ---------------------------------------------------------------------------
extern "C" void kernel_launch(void* const* d_in, const int* in_sizes, int n_in,
                              void* d_out, int out_size, void* d_ws, size_t ws_size,
                              hipStream_t stream) {
    const float* x      = (const float*)d_in[0];
    const float* W_patch= (const float*)d_in[1];
    const float* b_patch= (const float*)d_in[2];
    const float* cls_tok= (const float*)d_in[3];
    const float* pos_emb= (const float*)d_in[4];
    const float* Wkl = (const float*)d_in[5];   const float* bkl = (const float*)d_in[6];
    const float* Wvl = (const float*)d_in[7];   const float* bvl = (const float*)d_in[8];
    const float* Wkr = (const float*)d_in[9];   const float* bkr = (const float*)d_in[10];
    const float* Wvr = (const float*)d_in[11];  const float* bvr = (const float*)d_in[12];
    const float* Wkt = (const float*)d_in[13];  const float* bkt = (const float*)d_in[14];
    const float* Wvt = (const float*)d_in[15];  const float* bvt = (const float*)d_in[16];
    const float* ln1_g = (const float*)d_in[17]; const float* ln1_b = (const float*)d_in[18];
    const float* Wqkv  = (const float*)d_in[19]; const float* bqkv  = (const float*)d_in[20];
    const float* Wo    = (const float*)d_in[21]; const float* bo    = (const float*)d_in[22];
    const float* ln2_g = (const float*)d_in[23]; const float* ln2_b = (const float*)d_in[24];
    const float* W1 = (const float*)d_in[25];   const float* b1 = (const float*)d_in[26];
    const float* W2 = (const float*)d_in[27];   const float* b2 = (const float*)d_in[28];
    const float* lnf_g = (const float*)d_in[29]; const float* lnf_b = (const float*)d_in[30];
    const float* W_head = (const float*)d_in[31]; const float* b_head = (const float*)d_in[32];

    // Workspace layout (fp32): total 20,979,712 floats = ~84 MB
    float* ws  = (float*)d_ws;
    float* h0  = ws;                       // MS*E
    float* h1  = h0 + (size_t)MS * E;      // MS*E
    float* xn  = h1 + (size_t)MS * E;      // MS*E
    float* ob  = xn + (size_t)MS * E;      // MS*E
    float* qk  = ob + (size_t)MS * E;      // MS*768
    float* ff  = qk + (size_t)MS * 768;    // MS*1536 (FF runs in 2 chunks)

    patch_embed_kernel<<<MS, 256, 0, stream>>>(x, W_patch, b_patch, cls_tok, pos_emb, h0);
    rag_kernel<<<Bz - 2, 256, 0, stream>>>(h0, h1, Wkl, bkl, Wvl, bvl,
                                           Wkr, bkr, Wvr, bvr, Wkt, bkt, Wvt, bvt);
    copy_edges<<<(2 * S * E + 255) / 256, 256, 0, stream>>>(h0, h1);

    const int gy = (MS + 63) / 64;   // 99 M-tiles
    for (int l = 0; l < Ln; l++) {
        ln_kernel<<<MS, 256, 0, stream>>>(h1, xn, ln1_g + l * E, ln1_b + l * E);
        gemm_kernel<0, 0><<<dim3(12, gy), 256, 0, stream>>>(
            xn, 256, Wqkv + (size_t)l * 768 * 256, 256, bqkv + l * 768,
            qk, 768, MS, 768, 256);
        attn_kernel<<<Bz * Hn, 256, 0, stream>>>(qk, ob);
        gemm_kernel<0, 1><<<dim3(4, gy), 256, 0, stream>>>(
            ob, 256, Wo + (size_t)l * 256 * 256, 256, bo + l * 256,
            h1, 256, MS, 256, 256);
        ln_kernel<<<MS, 256, 0, stream>>>(h1, xn, ln2_g + l * E, ln2_b + l * E);
        for (int c = 0; c < 2; c++) {
            gemm_kernel<1, 0><<<dim3(24, gy), 256, 0, stream>>>(
                xn, 256, W1 + (size_t)l * Fd * 256 + (size_t)c * 1536 * 256, 256,
                b1 + l * Fd + c * 1536, ff, 1536, MS, 1536, 256);
            gemm_kernel<0, 1><<<dim3(4, gy), 256, 0, stream>>>(
                ff, 1536, W2 + (size_t)l * 256 * Fd + c * 1536, 3072,
                (c == 0 ? b2 + l * 256 : nullptr), h1, 256, MS, 256, 1536);
        }
    }
    head_kernel<<<Bz, 256, 0, stream>>>(h1, lnf_g, lnf_b, W_head, b_head, (float*)d_out);
}

// Round 2
// 3302.733 us; speedup vs baseline: 3.1614x; 3.1614x over previous
//
#include <hip/hip_runtime.h>
#include <hip/hip_bf16.h>
#include <math.h>

// Problem constants
constexpr int Bz  = 32;
constexpr int S   = 197;
constexpr int E   = 256;
constexpr int Hn  = 16;
constexpr int HD  = 16;
constexpr int Fd  = 3072;
constexpr int Ln  = 12;
constexpr int MS  = Bz * S;         // 6304 tokens
constexpr int MP  = 6400;           // padded to 50 * 128 for MFMA GEMM tiles
constexpr int DVL = 50, DVR = 49, DVT = 49;

typedef __attribute__((ext_vector_type(8))) short short8;   // 8 bf16 = 4 VGPRs
typedef __attribute__((ext_vector_type(4))) float f32x4;

__device__ __forceinline__ unsigned short f2bf(float f) {
    unsigned int u = __float_as_uint(f);
    u = (u + 0x7FFFu + ((u >> 16) & 1u)) >> 16;             // RNE
    return (unsigned short)u;
}

// ---------------------------------------------------------------------------
// block-wide reduce (256 threads). op: 0=sum, 1=max. Returns value to all.
__device__ __forceinline__ float block_reduce(float v, float* red, int op) {
    int e = threadIdx.x;
    red[e] = v;
    __syncthreads();
    for (int s2 = 128; s2 > 0; s2 >>= 1) {
        if (e < s2) red[e] = op ? fmaxf(red[e], red[e + s2]) : red[e] + red[e + s2];
        __syncthreads();
    }
    float r = red[0];
    __syncthreads();
    return r;
}

// ---------------------------------------------------------------------------
// Patch embedding + cls token + pos emb. One block per token (B*S blocks).
__global__ __launch_bounds__(256) void patch_embed_kernel(
        const float* __restrict__ x, const float* __restrict__ Wp,
        const float* __restrict__ bp, const float* __restrict__ cls,
        const float* __restrict__ pos, float* __restrict__ h) {
    int tok = blockIdx.x;          // 0..MS-1
    int b = tok / S, s = tok % S;
    int e = threadIdx.x;           // 0..255
    if (s == 0) {
        h[(size_t)tok * E + e] = cls[e] + pos[e];
        return;
    }
    __shared__ float patch[256];
    int pi = s - 1;
    int i = pi / 14, j = pi % 14;
    int pr = e / 16, pc = e % 16;
    patch[e] = x[((size_t)(b * 224 + i * 16 + pr)) * 224 + j * 16 + pc];
    __syncthreads();
    float acc = bp[e];
    const float* w = Wp + (size_t)e * 256;
    #pragma unroll 8
    for (int k = 0; k < 256; k++) acc += patch[k] * w[k];
    h[(size_t)tok * E + e] = acc + pos[(size_t)s * E + e];
}

// ---------------------------------------------------------------------------
// One rag branch (factored: softmax@x then Wv matvec — exact up to rounding).
__device__ void rag_branch(const float* __restrict__ xsrc,
                           const float* __restrict__ Wk, const float* __restrict__ bk,
                           const float* __restrict__ Wv, const float* __restrict__ bv,
                           int dv, const float* __restrict__ key,
                           float* u, float* a, float* f, int fo, float* red) {
    int e = threadIdx.x;
    float uu = 0.f;
    for (int i = 0; i < 256; i++) uu += Wk[(size_t)i * 256 + e] * key[i];
    u[e] = uu;
    float c = block_reduce(bk[e] * key[e], red, 0);   // barrier also publishes u[]
    float sc = -1e30f;
    if (e < S) {
        float v = c;
        const float* row = xsrc + (size_t)e * E;
        for (int k = 0; k < 256; k++) v += row[k] * u[k];
        sc = v * 0.0625f;                              // 1/sqrt(E)
    }
    float mx = block_reduce(sc, red, 1);
    float ex = (e < S) ? expf(sc - mx) : 0.f;
    float denom = block_reduce(ex, red, 0);
    a[e] = ex / denom;
    __syncthreads();
    float xb = 0.f;
    for (int s = 0; s < S; s++) xb += a[s] * xsrc[(size_t)s * E + e];
    __syncthreads();          // everyone done reading u before overwrite
    u[e] = xb;
    __syncthreads();
    if (e < dv) {
        float r = bv[e];
        const float* wrow = Wv + (size_t)e * E;
        for (int k = 0; k < 256; k++) r += wrow[k] * u[k];
        f[fo + e] = r;
    }
    __syncthreads();
}

// One block per mid sample t=0..29: xl=h0[t], xt=h0[t+1], xr=h0[t+2].
__global__ __launch_bounds__(256) void rag_kernel(
        const float* __restrict__ h0, float* __restrict__ h1,
        const float* __restrict__ Wkl, const float* __restrict__ bkl,
        const float* __restrict__ Wvl, const float* __restrict__ bvl,
        const float* __restrict__ Wkr, const float* __restrict__ bkr,
        const float* __restrict__ Wvr, const float* __restrict__ bvr,
        const float* __restrict__ Wkt, const float* __restrict__ bkt,
        const float* __restrict__ Wvt, const float* __restrict__ bvt) {
    int t = blockIdx.x;
    int e = threadIdx.x;
    const float* xl = h0 + (size_t)t * S * E;
    const float* xt = xl + (size_t)S * E;
    const float* xr = xt + (size_t)S * E;
    __shared__ float rt[256], ml[256], mr[256], u[256], a[256], f[256], red[256];
    float sl = 0.f, st = 0.f, sr = 0.f;
    for (int s = 0; s < S; s++) {
        sl += xl[(size_t)s * E + e];
        st += xt[(size_t)s * E + e];
        sr += xr[(size_t)s * E + e];
    }
    const float invS = 1.f / (float)S;
    rt[e] = st * invS; ml[e] = sl * invS; mr[e] = sr * invS;
    __syncthreads();
    rag_branch(xl, Wkl, bkl, Wvl, bvl, DVL, rt, u, a, f, 0, red);           // rl
    rag_branch(xt, Wkt, bkt, Wvt, bvt, DVT, ml, u, a, f, DVL, red);          // rtl
    rag_branch(xt, Wkt, bkt, Wvt, bvt, DVT, mr, u, a, f, DVL + DVT, red);    // rtr
    rag_branch(xr, Wkr, bkr, Wvr, bvr, DVR, rt, u, a, f, DVL + 2 * DVT, red);// rr
    float rte = rt[e];
    float* outp = h1 + ((size_t)(t + 1) * S) * E;
    for (int s = 0; s < S; s++) outp[(size_t)s * E + e] = f[s] * rte;
}

// copy h0 samples 0 and 31 into h1
__global__ __launch_bounds__(256) void copy_edges(const float* __restrict__ h0,
                                                  float* __restrict__ h1) {
    int i = blockIdx.x * 256 + threadIdx.x;
    int n = S * E;
    if (i < n) h1[i] = h0[i];
    else if (i < 2 * n) {
        int j = i - n;
        size_t o = (size_t)31 * S * E + j;
        h1[o] = h0[o];
    }
}

// ---------------------------------------------------------------------------
// LayerNorm over E=256, fp32 in -> bf16 out. One block per token.
__global__ __launch_bounds__(256) void ln_kernel(const float* __restrict__ in,
                                                 unsigned short* __restrict__ out,
                                                 const float* __restrict__ g,
                                                 const float* __restrict__ b) {
    __shared__ float red[256];
    int tok = blockIdx.x, e = threadIdx.x;
    float v = in[(size_t)tok * E + e];
    float mean = block_reduce(v, red, 0) * (1.f / 256.f);
    float d = v - mean;
    float var = block_reduce(d * d, red, 0) * (1.f / 256.f);
    out[(size_t)tok * E + e] = f2bf(d * rsqrtf(var + 1e-5f) * g[e] + b[e]);
}

// ---------------------------------------------------------------------------
// Per-layer weight conversion fp32 -> bf16 into staging buffer.
// Segments: [0,196608) Wqkv | [196608,262144) Wo | [262144,1048576) W1 |
//           [1048576,1835008) W2.   Grid covers 458752 float4s.
__global__ __launch_bounds__(256) void convert_w_kernel(
        const float* __restrict__ wqkv, const float* __restrict__ wo,
        const float* __restrict__ w1, const float* __restrict__ w2,
        unsigned short* __restrict__ out) {
    int idx = blockIdx.x * 256 + threadIdx.x;       // 0..458751
    int i4 = idx * 4;
    const float* src;
    if (i4 < 196608)       src = wqkv + i4;
    else if (i4 < 262144)  src = wo + (i4 - 196608);
    else if (i4 < 1048576) src = w1 + (i4 - 262144);
    else                   src = w2 + (i4 - 1048576);
    float4 v = *(const float4*)src;
    ushort4 o;
    o.x = f2bf(v.x); o.y = f2bf(v.y); o.z = f2bf(v.z); o.w = f2bf(v.w);
    *(ushort4*)(out + i4) = o;
}

// ---------------------------------------------------------------------------
// bf16 MFMA GEMM: C[M,N] = op( A[MP,K] @ W[N,K]^T + bias )
// 128x128 tile, BK=32, 256 threads (4 waves, each 64x64 = 4x4 frags of
// 16x16x32 MFMA). LDS row stride 40 elems (80 B = 20 banks: 8 rows cycle all
// 32 banks, 2-way residual aliasing is free). M padded to MP (multiple of
// 128); N, K multiples of 128/32. No bounds checks anywhere.
// MODE 0: fp32 store (+bias) | MODE 1: fp32 += (+bias) | MODE 2: gelu -> bf16
template <int MODE>
__global__ __launch_bounds__(256) void mfma_gemm(
        const unsigned short* __restrict__ A, int lda,
        const unsigned short* __restrict__ W, int ldw,
        const float* __restrict__ bias,
        void* __restrict__ Cv, int ldc, int K) {
    __shared__ unsigned short As[128 * 40];
    __shared__ unsigned short Bs[128 * 40];
    const int m0 = blockIdx.y * 128, n0 = blockIdx.x * 128;
    const int tid  = threadIdx.x;
    const int wave = tid >> 6, lane = tid & 63;
    const int wm = (wave >> 1) * 64, wn = (wave & 1) * 64;
    const int lr = lane & 15, kg = lane >> 4;           // frag row / k-group
    const int srow = tid >> 2, scol = (tid & 3) * 8;    // staging coords
    f32x4 acc[4][4] = {};
    for (int k0 = 0; k0 < K; k0 += 32) {
        *(short8*)&As[(srow)      * 40 + scol] = *(const short8*)&A[(size_t)(m0 + srow)      * lda + k0 + scol];
        *(short8*)&As[(srow + 64) * 40 + scol] = *(const short8*)&A[(size_t)(m0 + srow + 64) * lda + k0 + scol];
        *(short8*)&Bs[(srow)      * 40 + scol] = *(const short8*)&W[(size_t)(n0 + srow)      * ldw + k0 + scol];
        *(short8*)&Bs[(srow + 64) * 40 + scol] = *(const short8*)&W[(size_t)(n0 + srow + 64) * ldw + k0 + scol];
        __syncthreads();
        short8 af[4], bfr[4];
        #pragma unroll
        for (int i = 0; i < 4; i++) af[i]  = *(short8*)&As[(wm + i * 16 + lr) * 40 + kg * 8];
        #pragma unroll
        for (int j = 0; j < 4; j++) bfr[j] = *(short8*)&Bs[(wn + j * 16 + lr) * 40 + kg * 8];
        #pragma unroll
        for (int i = 0; i < 4; i++)
            #pragma unroll
            for (int j = 0; j < 4; j++)
                acc[i][j] = __builtin_amdgcn_mfma_f32_16x16x32_bf16(af[i], bfr[j], acc[i][j], 0, 0, 0);
        __syncthreads();
    }
    // epilogue: C/D layout col=lane&15, row=kg*4+reg
    #pragma unroll
    for (int j = 0; j < 4; j++) {
        int n = n0 + wn + j * 16 + lr;
        float bv = bias ? bias[n] : 0.f;
        #pragma unroll
        for (int i = 0; i < 4; i++) {
            #pragma unroll
            for (int r = 0; r < 4; r++) {
                size_t m = (size_t)(m0 + wm + i * 16 + kg * 4 + r);
                float v = acc[i][j][r] + bv;
                if (MODE == 0) ((float*)Cv)[m * ldc + n] = v;
                if (MODE == 1) ((float*)Cv)[m * ldc + n] += v;
                if (MODE == 2) {
                    v = 0.5f * v * (1.f + erff(v * 0.70710678118654752f));
                    ((unsigned short*)Cv)[m * ldc + n] = f2bf(v);
                }
            }
        }
    }
}

// ---------------------------------------------------------------------------
// Attention: one block per (sample, head). K/V staged in LDS; online softmax.
// qkv fp32 in, bf16 out (feeds proj GEMM).
__global__ __launch_bounds__(256) void attn_kernel(const float* __restrict__ qkv,
                                                   unsigned short* __restrict__ o) {
    int bh = blockIdx.x;
    int b = bh / Hn, hh = bh % Hn;
    __shared__ float Ks[S][HD];
    __shared__ float Vs[S][HD];
    int tid = threadIdx.x;
    for (int i = tid; i < S * HD; i += 256) {
        int s = i / HD, d = i % HD;
        size_t base = ((size_t)(b * S + s)) * 768 + hh * HD + d;
        Ks[s][d] = qkv[base + 256];
        Vs[s][d] = qkv[base + 512];
    }
    __syncthreads();
    int s = tid;
    if (s < S) {
        float q[HD];
        const float* qp = qkv + ((size_t)(b * S + s)) * 768 + hh * HD;
        #pragma unroll
        for (int d = 0; d < HD; d++) q[d] = qp[d] * 0.25f;   // 1/sqrt(HD)
        float m = -1e30f, l = 0.f, acc[HD] = {};
        for (int k = 0; k < S; k++) {
            float sc = 0.f;
            #pragma unroll
            for (int d = 0; d < HD; d++) sc += q[d] * Ks[k][d];
            float mn = fmaxf(m, sc);
            float corr = expf(m - mn);
            float p = expf(sc - mn);
            l = l * corr + p;
            #pragma unroll
            for (int d = 0; d < HD; d++) acc[d] = acc[d] * corr + p * Vs[k][d];
            m = mn;
        }
        float inv = 1.f / l;
        unsigned short* op = o + ((size_t)(b * S + s)) * E + hh * HD;
        #pragma unroll
        for (int d = 0; d < HD; d++) op[d] = f2bf(acc[d] * inv);
    }
}

// ---------------------------------------------------------------------------
// Final LN on cls token + head GEMM. One block per sample.
__global__ __launch_bounds__(256) void head_kernel(
        const float* __restrict__ h, const float* __restrict__ g,
        const float* __restrict__ bb, const float* __restrict__ Wh,
        const float* __restrict__ bh, float* __restrict__ out) {
    __shared__ float red[256];
    __shared__ float xs[256];
    int b = blockIdx.x, e = threadIdx.x;
    float v = h[((size_t)(b * S)) * E + e];
    float mean = block_reduce(v, red, 0) * (1.f / 256.f);
    float d = v - mean;
    float var = block_reduce(d * d, red, 0) * (1.f / 256.f);
    float xn = d * rsqrtf(var + 1e-5f) * g[e] + bb[e];
    xs[e] = xn;
    __syncthreads();
    for (int n = 0; n < 8; n++) {
        float s = block_reduce(xs[e] * Wh[(size_t)n * 256 + e], red, 0);
        if (e == 0) out[b * 8 + n] = s + bh[n];
    }
}

// ---------------------------------------------------------------------------
extern "C" void kernel_launch(void* const* d_in, const int* in_sizes, int n_in,
                              void* d_out, int out_size, void* d_ws, size_t ws_size,
                              hipStream_t stream) {
    const float* x      = (const float*)d_in[0];
    const float* W_patch= (const float*)d_in[1];
    const float* b_patch= (const float*)d_in[2];
    const float* cls_tok= (const float*)d_in[3];
    const float* pos_emb= (const float*)d_in[4];
    const float* Wkl = (const float*)d_in[5];   const float* bkl = (const float*)d_in[6];
    const float* Wvl = (const float*)d_in[7];   const float* bvl = (const float*)d_in[8];
    const float* Wkr = (const float*)d_in[9];   const float* bkr = (const float*)d_in[10];
    const float* Wvr = (const float*)d_in[11];  const float* bvr = (const float*)d_in[12];
    const float* Wkt = (const float*)d_in[13];  const float* bkt = (const float*)d_in[14];
    const float* Wvt = (const float*)d_in[15];  const float* bvt = (const float*)d_in[16];
    const float* ln1_g = (const float*)d_in[17]; const float* ln1_b = (const float*)d_in[18];
    const float* Wqkv  = (const float*)d_in[19]; const float* bqkv  = (const float*)d_in[20];
    const float* Wo    = (const float*)d_in[21]; const float* bo    = (const float*)d_in[22];
    const float* ln2_g = (const float*)d_in[23]; const float* ln2_b = (const float*)d_in[24];
    const float* W1 = (const float*)d_in[25];   const float* b1 = (const float*)d_in[26];
    const float* W2 = (const float*)d_in[27];   const float* b2 = (const float*)d_in[28];
    const float* lnf_g = (const float*)d_in[29]; const float* lnf_b = (const float*)d_in[30];
    const float* W_head = (const float*)d_in[31]; const float* b_head = (const float*)d_in[32];

    // Workspace layout (bytes):
    //  h0  fp32 MP*256   6,553,600
    //  h1  fp32 MP*256   6,553,600
    //  qk  fp32 MP*768  19,660,800
    //  xnb bf16 MP*256   3,276,800
    //  ob  bf16 MP*256   3,276,800
    //  ff  bf16 MP*3072 39,321,600
    //  wb  bf16 1835008  3,670,016   -> total 82,313,216 B
    char* p = (char*)d_ws;
    float* h0 = (float*)p;                   p += (size_t)MP * 256 * 4;
    float* h1 = (float*)p;                   p += (size_t)MP * 256 * 4;
    float* qk = (float*)p;                   p += (size_t)MP * 768 * 4;
    unsigned short* xnb = (unsigned short*)p; p += (size_t)MP * 256 * 2;
    unsigned short* ob  = (unsigned short*)p; p += (size_t)MP * 256 * 2;
    unsigned short* ff  = (unsigned short*)p; p += (size_t)MP * 3072 * 2;
    unsigned short* wb  = (unsigned short*)p;
    unsigned short* wqkv_b = wb;             // 196608
    unsigned short* wo_b   = wb + 196608;    // 65536
    unsigned short* w1_b   = wb + 262144;    // 786432
    unsigned short* w2_b   = wb + 1048576;   // 786432

    patch_embed_kernel<<<MS, 256, 0, stream>>>(x, W_patch, b_patch, cls_tok, pos_emb, h0);
    rag_kernel<<<Bz - 2, 256, 0, stream>>>(h0, h1, Wkl, bkl, Wvl, bvl,
                                           Wkr, bkr, Wvr, bvr, Wkt, bkt, Wvt, bvt);
    copy_edges<<<(2 * S * E + 255) / 256, 256, 0, stream>>>(h0, h1);

    const int gy = MP / 128;   // 50 M-tiles
    for (int l = 0; l < Ln; l++) {
        convert_w_kernel<<<1792, 256, 0, stream>>>(
            Wqkv + (size_t)l * 768 * 256, Wo + (size_t)l * 256 * 256,
            W1 + (size_t)l * Fd * 256, W2 + (size_t)l * 256 * Fd, wb);
        ln_kernel<<<MS, 256, 0, stream>>>(h1, xnb, ln1_g + l * E, ln1_b + l * E);
        mfma_gemm<0><<<dim3(6, gy), 256, 0, stream>>>(
            xnb, 256, wqkv_b, 256, bqkv + l * 768, qk, 768, 256);
        attn_kernel<<<Bz * Hn, 256, 0, stream>>>(qk, ob);
        mfma_gemm<1><<<dim3(2, gy), 256, 0, stream>>>(
            ob, 256, wo_b, 256, bo + l * 256, h1, 256, 256);
        ln_kernel<<<MS, 256, 0, stream>>>(h1, xnb, ln2_g + l * E, ln2_b + l * E);
        mfma_gemm<2><<<dim3(24, gy), 256, 0, stream>>>(
            xnb, 256, w1_b, 256, b1 + l * Fd, ff, 3072, 256);
        mfma_gemm<1><<<dim3(2, gy), 256, 0, stream>>>(
            ff, 3072, w2_b, 3072, b2 + l * 256, h1, 256, 3072);
    }
    head_kernel<<<Bz, 256, 0, stream>>>(h1, lnf_g, lnf_b, W_head, b_head, (float*)d_out);
}

// Round 3
// 2757.696 us; speedup vs baseline: 3.7862x; 1.1976x over previous
//
#include <hip/hip_runtime.h>
#include <hip/hip_bf16.h>
#include <math.h>

// Problem constants
constexpr int Bz  = 32;
constexpr int S   = 197;
constexpr int E   = 256;
constexpr int Hn  = 16;
constexpr int HD  = 16;
constexpr int Fd  = 3072;
constexpr int Ln  = 12;
constexpr int MS  = Bz * S;         // 6304 tokens
constexpr int MP  = 6400;           // padded to 50 * 128 for MFMA GEMM tiles
constexpr int NPAT = 6272;          // 32*196 patches = 49*128 exactly
constexpr int DVL = 50, DVR = 49, DVT = 49;

typedef __attribute__((ext_vector_type(8))) short short8;   // 8 bf16 = 4 VGPRs
typedef __attribute__((ext_vector_type(4))) float f32x4;

__device__ __forceinline__ unsigned short f2bf(float f) {
    unsigned int u = __float_as_uint(f);
    u = (u + 0x7FFFu + ((u >> 16) & 1u)) >> 16;             // RNE
    return (unsigned short)u;
}

// ---------------------------------------------------------------------------
// block-wide reduce (256 thr): wave shuffle + 4-slot LDS. op: 0=sum, 1=max.
__device__ __forceinline__ float block_reduce(float v, float* red4, int op) {
    #pragma unroll
    for (int off = 32; off > 0; off >>= 1) {
        float o = __shfl_xor(v, off, 64);
        v = op ? fmaxf(v, o) : v + o;
    }
    int w = threadIdx.x >> 6;
    if ((threadIdx.x & 63) == 0) red4[w] = v;
    __syncthreads();
    float r = op ? fmaxf(fmaxf(red4[0], red4[1]), fmaxf(red4[2], red4[3]))
                 : (red4[0] + red4[1] + red4[2] + red4[3]);
    __syncthreads();
    return r;
}

// ---------------------------------------------------------------------------
// Patchify: x (B,1,224,224) -> bf16 A[6272][256], A[b*196+q][pr*16+pc].
__global__ __launch_bounds__(256) void patchify_kernel(
        const float* __restrict__ x, unsigned short* __restrict__ Ab) {
    int pi = blockIdx.x;                 // 0..6271
    int b = pi / 196, q = pi % 196;
    int i = q / 14, j = q % 14;
    int e = threadIdx.x, pr = e >> 4, pc = e & 15;
    float v = x[((size_t)(b * 224 + i * 16 + pr)) * 224 + j * 16 + pc];
    Ab[(size_t)pi * 256 + e] = f2bf(v);
}

// cls token rows of h0
__global__ __launch_bounds__(256) void cls_pos_kernel(
        const float* __restrict__ cls, const float* __restrict__ pos,
        float* __restrict__ h0) {
    int b = blockIdx.x, e = threadIdx.x;
    h0[(size_t)(b * S) * E + e] = cls[e] + pos[e];
}

// fp32 -> bf16, 4 elems/thread (count must be multiple of 1024 per grid calc)
__global__ __launch_bounds__(256) void convert_kernel(
        const float* __restrict__ src, unsigned short* __restrict__ dst) {
    int i4 = (blockIdx.x * 256 + threadIdx.x) * 4;
    float4 v = *(const float4*)(src + i4);
    ushort4 o;
    o.x = f2bf(v.x); o.y = f2bf(v.y); o.z = f2bf(v.z); o.w = f2bf(v.w);
    *(ushort4*)(dst + i4) = o;
}

// ---------------------------------------------------------------------------
// One rag branch (factored: softmax@x then Wv matvec — exact up to rounding).
__device__ void rag_branch(const float* __restrict__ xsrc,
                           const float* __restrict__ Wk, const float* __restrict__ bk,
                           const float* __restrict__ Wv, const float* __restrict__ bv,
                           int dv, const float* __restrict__ key,
                           float* u, float* a, float* f, int fo, float* red4) {
    int e = threadIdx.x;
    float uu = 0.f;
    for (int i = 0; i < 256; i++) uu += Wk[(size_t)i * 256 + e] * key[i];
    u[e] = uu;
    float c = block_reduce(bk[e] * key[e], red4, 0);   // barrier also publishes u[]
    float sc = -1e30f;
    if (e < S) {
        float v = c;
        const float* row = xsrc + (size_t)e * E;
        for (int k = 0; k < 256; k++) v += row[k] * u[k];
        sc = v * 0.0625f;                              // 1/sqrt(E)
    }
    float mx = block_reduce(sc, red4, 1);
    float ex = (e < S) ? expf(sc - mx) : 0.f;
    float denom = block_reduce(ex, red4, 0);
    a[e] = ex / denom;
    __syncthreads();
    float xb = 0.f;
    for (int s = 0; s < S; s++) xb += a[s] * xsrc[(size_t)s * E + e];
    __syncthreads();          // everyone done reading u before overwrite
    u[e] = xb;
    __syncthreads();
    if (e < dv) {
        float r = bv[e];
        const float* wrow = Wv + (size_t)e * E;
        for (int k = 0; k < 256; k++) r += wrow[k] * u[k];
        f[fo + e] = r;
    }
    __syncthreads();
}

// One block per mid sample t=0..29: xl=h0[t], xt=h0[t+1], xr=h0[t+2].
__global__ __launch_bounds__(256) void rag_kernel(
        const float* __restrict__ h0, float* __restrict__ h1,
        const float* __restrict__ Wkl, const float* __restrict__ bkl,
        const float* __restrict__ Wvl, const float* __restrict__ bvl,
        const float* __restrict__ Wkr, const float* __restrict__ bkr,
        const float* __restrict__ Wvr, const float* __restrict__ bvr,
        const float* __restrict__ Wkt, const float* __restrict__ bkt,
        const float* __restrict__ Wvt, const float* __restrict__ bvt) {
    int t = blockIdx.x;
    int e = threadIdx.x;
    const float* xl = h0 + (size_t)t * S * E;
    const float* xt = xl + (size_t)S * E;
    const float* xr = xt + (size_t)S * E;
    __shared__ float rt[256], ml[256], mr[256], u[256], a[256], f[256], red4[4];
    float sl = 0.f, st = 0.f, sr = 0.f;
    for (int s = 0; s < S; s++) {
        sl += xl[(size_t)s * E + e];
        st += xt[(size_t)s * E + e];
        sr += xr[(size_t)s * E + e];
    }
    const float invS = 1.f / (float)S;
    rt[e] = st * invS; ml[e] = sl * invS; mr[e] = sr * invS;
    __syncthreads();
    rag_branch(xl, Wkl, bkl, Wvl, bvl, DVL, rt, u, a, f, 0, red4);           // rl
    rag_branch(xt, Wkt, bkt, Wvt, bvt, DVT, ml, u, a, f, DVL, red4);          // rtl
    rag_branch(xt, Wkt, bkt, Wvt, bvt, DVT, mr, u, a, f, DVL + DVT, red4);    // rtr
    rag_branch(xr, Wkr, bkr, Wvr, bvr, DVR, rt, u, a, f, DVL + 2 * DVT, red4);// rr
    float rte = rt[e];
    float* outp = h1 + ((size_t)(t + 1) * S) * E;
    for (int s = 0; s < S; s++) outp[(size_t)s * E + e] = f[s] * rte;
}

// copy h0 samples 0 and 31 into h1
__global__ __launch_bounds__(256) void copy_edges(const float* __restrict__ h0,
                                                  float* __restrict__ h1) {
    int i = blockIdx.x * 256 + threadIdx.x;
    int n = S * E;
    if (i < n) h1[i] = h0[i];
    else if (i < 2 * n) {
        int j = i - n;
        size_t o = (size_t)31 * S * E + j;
        h1[o] = h0[o];
    }
}

// ---------------------------------------------------------------------------
// LayerNorm over E=256, fp32 in -> bf16 out. One block per token.
__global__ __launch_bounds__(256) void ln_kernel(const float* __restrict__ in,
                                                 unsigned short* __restrict__ out,
                                                 const float* __restrict__ g,
                                                 const float* __restrict__ b) {
    __shared__ float red4[4];
    int tok = blockIdx.x, e = threadIdx.x;
    float v = in[(size_t)tok * E + e];
    float mean = block_reduce(v, red4, 0) * (1.f / 256.f);
    float d = v - mean;
    float var = block_reduce(d * d, red4, 0) * (1.f / 256.f);
    out[(size_t)tok * E + e] = f2bf(d * rsqrtf(var + 1e-5f) * g[e] + b[e]);
}

// ---------------------------------------------------------------------------
// Per-layer weight conversion fp32 -> bf16 into staging buffer.
__global__ __launch_bounds__(256) void convert_w_kernel(
        const float* __restrict__ wqkv, const float* __restrict__ wo,
        const float* __restrict__ w1, const float* __restrict__ w2,
        unsigned short* __restrict__ out) {
    int idx = blockIdx.x * 256 + threadIdx.x;       // 0..458751
    int i4 = idx * 4;
    const float* src;
    if (i4 < 196608)       src = wqkv + i4;
    else if (i4 < 262144)  src = wo + (i4 - 196608);
    else if (i4 < 1048576) src = w1 + (i4 - 262144);
    else                   src = w2 + (i4 - 1048576);
    float4 v = *(const float4*)src;
    ushort4 o;
    o.x = f2bf(v.x); o.y = f2bf(v.y); o.z = f2bf(v.z); o.w = f2bf(v.w);
    *(ushort4*)(out + i4) = o;
}

// ---------------------------------------------------------------------------
// bf16 MFMA GEMM, 128x128 tile, BK=32, 256 threads (4 waves of 64x64).
// LDS row stride 40 elems. MODE 0: fp32 store (+bias) | MODE 2: gelu -> bf16
template <int MODE>
__global__ __launch_bounds__(256) void mfma_gemm(
        const unsigned short* __restrict__ A, int lda,
        const unsigned short* __restrict__ W, int ldw,
        const float* __restrict__ bias,
        void* __restrict__ Cv, int ldc, int K) {
    __shared__ unsigned short As[128 * 40];
    __shared__ unsigned short Bs[128 * 40];
    const int m0 = blockIdx.y * 128, n0 = blockIdx.x * 128;
    const int tid  = threadIdx.x;
    const int wave = tid >> 6, lane = tid & 63;
    const int wm = (wave >> 1) * 64, wn = (wave & 1) * 64;
    const int lr = lane & 15, kg = lane >> 4;           // frag row / k-group
    const int srow = tid >> 2, scol = (tid & 3) * 8;    // staging coords
    f32x4 acc[4][4] = {};
    for (int k0 = 0; k0 < K; k0 += 32) {
        *(short8*)&As[(srow)      * 40 + scol] = *(const short8*)&A[(size_t)(m0 + srow)      * lda + k0 + scol];
        *(short8*)&As[(srow + 64) * 40 + scol] = *(const short8*)&A[(size_t)(m0 + srow + 64) * lda + k0 + scol];
        *(short8*)&Bs[(srow)      * 40 + scol] = *(const short8*)&W[(size_t)(n0 + srow)      * ldw + k0 + scol];
        *(short8*)&Bs[(srow + 64) * 40 + scol] = *(const short8*)&W[(size_t)(n0 + srow + 64) * ldw + k0 + scol];
        __syncthreads();
        short8 af[4], bfr[4];
        #pragma unroll
        for (int i = 0; i < 4; i++) af[i]  = *(short8*)&As[(wm + i * 16 + lr) * 40 + kg * 8];
        #pragma unroll
        for (int j = 0; j < 4; j++) bfr[j] = *(short8*)&Bs[(wn + j * 16 + lr) * 40 + kg * 8];
        #pragma unroll
        for (int i = 0; i < 4; i++)
            #pragma unroll
            for (int j = 0; j < 4; j++)
                acc[i][j] = __builtin_amdgcn_mfma_f32_16x16x32_bf16(af[i], bfr[j], acc[i][j], 0, 0, 0);
        __syncthreads();
    }
    #pragma unroll
    for (int j = 0; j < 4; j++) {
        int n = n0 + wn + j * 16 + lr;
        float bv = bias ? bias[n] : 0.f;
        #pragma unroll
        for (int i = 0; i < 4; i++) {
            #pragma unroll
            for (int r = 0; r < 4; r++) {
                size_t m = (size_t)(m0 + wm + i * 16 + kg * 4 + r);
                float v = acc[i][j][r] + bv;
                if (MODE == 0) ((float*)Cv)[m * ldc + n] = v;
                if (MODE == 2) {
                    v = 0.5f * v * (1.f + erff(v * 0.70710678118654752f));
                    ((unsigned short*)Cv)[m * ldc + n] = f2bf(v);
                }
            }
        }
    }
}

// ---------------------------------------------------------------------------
// bf16 MFMA GEMM, 128x64 tile, BK=32, 4 waves (each 32 rows x 64 cols).
// MODE 1: fp32 += (+bias) | MODE 3: patch-embed epilogue (token remap + pos)
template <int MODE>
__global__ __launch_bounds__(256) void mfma_gemm64(
        const unsigned short* __restrict__ A, int lda,
        const unsigned short* __restrict__ W, int ldw,
        const float* __restrict__ bias,
        void* __restrict__ Cv, int ldc, int K,
        const float* __restrict__ pos) {
    __shared__ unsigned short As[128 * 40];
    __shared__ unsigned short Bs[64 * 40];
    const int m0 = blockIdx.y * 128, n0 = blockIdx.x * 64;
    const int tid  = threadIdx.x;
    const int wave = tid >> 6, lane = tid & 63;
    const int wm = wave * 32;
    const int lr = lane & 15, kg = lane >> 4;
    const int srow = tid >> 2, scol = (tid & 3) * 8;
    f32x4 acc[2][4] = {};
    for (int k0 = 0; k0 < K; k0 += 32) {
        *(short8*)&As[(srow)      * 40 + scol] = *(const short8*)&A[(size_t)(m0 + srow)      * lda + k0 + scol];
        *(short8*)&As[(srow + 64) * 40 + scol] = *(const short8*)&A[(size_t)(m0 + srow + 64) * lda + k0 + scol];
        *(short8*)&Bs[(srow)      * 40 + scol] = *(const short8*)&W[(size_t)(n0 + srow)      * ldw + k0 + scol];
        __syncthreads();
        short8 af[2], bfr[4];
        #pragma unroll
        for (int i = 0; i < 2; i++) af[i]  = *(short8*)&As[(wm + i * 16 + lr) * 40 + kg * 8];
        #pragma unroll
        for (int j = 0; j < 4; j++) bfr[j] = *(short8*)&Bs[(j * 16 + lr) * 40 + kg * 8];
        #pragma unroll
        for (int i = 0; i < 2; i++)
            #pragma unroll
            for (int j = 0; j < 4; j++)
                acc[i][j] = __builtin_amdgcn_mfma_f32_16x16x32_bf16(af[i], bfr[j], acc[i][j], 0, 0, 0);
        __syncthreads();
    }
    #pragma unroll
    for (int j = 0; j < 4; j++) {
        int n = n0 + j * 16 + lr;
        float bv = bias ? bias[n] : 0.f;
        #pragma unroll
        for (int i = 0; i < 2; i++) {
            #pragma unroll
            for (int r = 0; r < 4; r++) {
                int m = m0 + wm + i * 16 + kg * 4 + r;
                float v = acc[i][j][r] + bv;
                if (MODE == 1) ((float*)Cv)[(size_t)m * ldc + n] += v;
                if (MODE == 3) {
                    int b = m / 196, s = m - b * 196 + 1;   // token remap
                    ((float*)Cv)[((size_t)(b * S + s)) * E + n] = v + pos[(size_t)s * E + n];
                }
            }
        }
    }
}

// ---------------------------------------------------------------------------
// Attention: one block per (sample, head). K/V staged in LDS; online softmax.
__global__ __launch_bounds__(256) void attn_kernel(const float* __restrict__ qkv,
                                                   unsigned short* __restrict__ o) {
    int bh = blockIdx.x;
    int b = bh / Hn, hh = bh % Hn;
    __shared__ float Ks[S][HD];
    __shared__ float Vs[S][HD];
    int tid = threadIdx.x;
    for (int i = tid; i < S * HD; i += 256) {
        int s = i / HD, d = i % HD;
        size_t base = ((size_t)(b * S + s)) * 768 + hh * HD + d;
        Ks[s][d] = qkv[base + 256];
        Vs[s][d] = qkv[base + 512];
    }
    __syncthreads();
    int s = tid;
    if (s < S) {
        float q[HD];
        const float* qp = qkv + ((size_t)(b * S + s)) * 768 + hh * HD;
        #pragma unroll
        for (int d = 0; d < HD; d++) q[d] = qp[d] * 0.25f;   // 1/sqrt(HD)
        float m = -1e30f, l = 0.f, acc[HD] = {};
        for (int k = 0; k < S; k++) {
            float sc = 0.f;
            #pragma unroll
            for (int d = 0; d < HD; d++) sc += q[d] * Ks[k][d];
            float mn = fmaxf(m, sc);
            float corr = expf(m - mn);
            float p = expf(sc - mn);
            l = l * corr + p;
            #pragma unroll
            for (int d = 0; d < HD; d++) acc[d] = acc[d] * corr + p * Vs[k][d];
            m = mn;
        }
        float inv = 1.f / l;
        unsigned short* op = o + ((size_t)(b * S + s)) * E + hh * HD;
        #pragma unroll
        for (int d = 0; d < HD; d++) op[d] = f2bf(acc[d] * inv);
    }
}

// ---------------------------------------------------------------------------
// Final LN on cls token + head GEMM. One block per sample.
__global__ __launch_bounds__(256) void head_kernel(
        const float* __restrict__ h, const float* __restrict__ g,
        const float* __restrict__ bb, const float* __restrict__ Wh,
        const float* __restrict__ bh, float* __restrict__ out) {
    __shared__ float red4[4];
    __shared__ float xs[256];
    int b = blockIdx.x, e = threadIdx.x;
    float v = h[((size_t)(b * S)) * E + e];
    float mean = block_reduce(v, red4, 0) * (1.f / 256.f);
    float d = v - mean;
    float var = block_reduce(d * d, red4, 0) * (1.f / 256.f);
    float xn = d * rsqrtf(var + 1e-5f) * g[e] + bb[e];
    xs[e] = xn;
    __syncthreads();
    for (int n = 0; n < 8; n++) {
        float s = block_reduce(xs[e] * Wh[(size_t)n * 256 + e], red4, 0);
        if (e == 0) out[b * 8 + n] = s + bh[n];
    }
}

// ---------------------------------------------------------------------------
extern "C" void kernel_launch(void* const* d_in, const int* in_sizes, int n_in,
                              void* d_out, int out_size, void* d_ws, size_t ws_size,
                              hipStream_t stream) {
    const float* x      = (const float*)d_in[0];
    const float* W_patch= (const float*)d_in[1];
    const float* b_patch= (const float*)d_in[2];
    const float* cls_tok= (const float*)d_in[3];
    const float* pos_emb= (const float*)d_in[4];
    const float* Wkl = (const float*)d_in[5];   const float* bkl = (const float*)d_in[6];
    const float* Wvl = (const float*)d_in[7];   const float* bvl = (const float*)d_in[8];
    const float* Wkr = (const float*)d_in[9];   const float* bkr = (const float*)d_in[10];
    const float* Wvr = (const float*)d_in[11];  const float* bvr = (const float*)d_in[12];
    const float* Wkt = (const float*)d_in[13];  const float* bkt = (const float*)d_in[14];
    const float* Wvt = (const float*)d_in[15];  const float* bvt = (const float*)d_in[16];
    const float* ln1_g = (const float*)d_in[17]; const float* ln1_b = (const float*)d_in[18];
    const float* Wqkv  = (const float*)d_in[19]; const float* bqkv  = (const float*)d_in[20];
    const float* Wo    = (const float*)d_in[21]; const float* bo    = (const float*)d_in[22];
    const float* ln2_g = (const float*)d_in[23]; const float* ln2_b = (const float*)d_in[24];
    const float* W1 = (const float*)d_in[25];   const float* b1 = (const float*)d_in[26];
    const float* W2 = (const float*)d_in[27];   const float* b2 = (const float*)d_in[28];
    const float* lnf_g = (const float*)d_in[29]; const float* lnf_b = (const float*)d_in[30];
    const float* W_head = (const float*)d_in[31]; const float* b_head = (const float*)d_in[32];

    // Workspace layout (bytes): total 82,313,216 B
    char* p = (char*)d_ws;
    float* h0 = (float*)p;                   p += (size_t)MP * 256 * 4;
    float* h1 = (float*)p;                   p += (size_t)MP * 256 * 4;
    float* qk = (float*)p;                   p += (size_t)MP * 768 * 4;
    unsigned short* xnb = (unsigned short*)p; p += (size_t)MP * 256 * 2;
    unsigned short* ob  = (unsigned short*)p; p += (size_t)MP * 256 * 2;
    unsigned short* ff  = (unsigned short*)p; p += (size_t)MP * 3072 * 2;
    unsigned short* wb  = (unsigned short*)p;
    unsigned short* wqkv_b = wb;             // 196608
    unsigned short* wo_b   = wb + 196608;    // 65536
    unsigned short* w1_b   = wb + 262144;    // 786432
    unsigned short* w2_b   = wb + 1048576;   // 786432

    // ---- patch embedding as MFMA GEMM ----
    convert_kernel<<<64, 256, 0, stream>>>(W_patch, wqkv_b);   // Wp bf16 (wb free pre-loop)
    patchify_kernel<<<NPAT, 256, 0, stream>>>(x, xnb);
    cls_pos_kernel<<<Bz, 256, 0, stream>>>(cls_tok, pos_emb, h0);
    mfma_gemm64<3><<<dim3(4, NPAT / 128), 256, 0, stream>>>(
        xnb, 256, wqkv_b, 256, b_patch, h0, 256, 256, pos_emb);

    rag_kernel<<<Bz - 2, 256, 0, stream>>>(h0, h1, Wkl, bkl, Wvl, bvl,
                                           Wkr, bkr, Wvr, bvr, Wkt, bkt, Wvt, bvt);
    copy_edges<<<(2 * S * E + 255) / 256, 256, 0, stream>>>(h0, h1);

    const int gy = MP / 128;   // 50 M-tiles
    for (int l = 0; l < Ln; l++) {
        convert_w_kernel<<<1792, 256, 0, stream>>>(
            Wqkv + (size_t)l * 768 * 256, Wo + (size_t)l * 256 * 256,
            W1 + (size_t)l * Fd * 256, W2 + (size_t)l * 256 * Fd, wb);
        ln_kernel<<<MS, 256, 0, stream>>>(h1, xnb, ln1_g + l * E, ln1_b + l * E);
        mfma_gemm<0><<<dim3(6, gy), 256, 0, stream>>>(
            xnb, 256, wqkv_b, 256, bqkv + l * 768, qk, 768, 256);
        attn_kernel<<<Bz * Hn, 256, 0, stream>>>(qk, ob);
        mfma_gemm64<1><<<dim3(4, gy), 256, 0, stream>>>(
            ob, 256, wo_b, 256, bo + l * 256, h1, 256, 256, nullptr);
        ln_kernel<<<MS, 256, 0, stream>>>(h1, xnb, ln2_g + l * E, ln2_b + l * E);
        mfma_gemm<2><<<dim3(24, gy), 256, 0, stream>>>(
            xnb, 256, w1_b, 256, b1 + l * Fd, ff, 3072, 256);
        mfma_gemm64<1><<<dim3(4, gy), 256, 0, stream>>>(
            ff, 3072, w2_b, 3072, b2 + l * 256, h1, 256, 3072, nullptr);
    }
    head_kernel<<<Bz, 256, 0, stream>>>(h1, lnf_g, lnf_b, W_head, b_head, (float*)d_out);
}

// Round 4
// 2429.961 us; speedup vs baseline: 4.2969x; 1.1349x over previous
//
#include <hip/hip_runtime.h>
#include <hip/hip_bf16.h>
#include <math.h>

// Problem constants
constexpr int Bz  = 32;
constexpr int S   = 197;
constexpr int E   = 256;
constexpr int Hn  = 16;
constexpr int HD  = 16;
constexpr int Fd  = 3072;
constexpr int Ln  = 12;
constexpr int MS  = Bz * S;         // 6304 tokens
constexpr int MP  = 6400;           // padded to 50 * 128 for MFMA GEMM tiles
constexpr int NPAT = 6272;          // 32*196 patches = 49*128 exactly
constexpr int DVL = 50, DVR = 49, DVT = 49;

typedef __attribute__((ext_vector_type(8))) short short8;   // 8 bf16 = 4 VGPRs
typedef __attribute__((ext_vector_type(4))) float f32x4;

__device__ __forceinline__ unsigned short f2bf(float f) {
    unsigned int u = __float_as_uint(f);
    u = (u + 0x7FFFu + ((u >> 16) & 1u)) >> 16;             // RNE
    return (unsigned short)u;
}

// async global->LDS, 16 B per lane. LDS dest is wave-uniform base + lane*16.
__device__ __forceinline__ void gload_lds16(const void* g, void* l) {
    __builtin_amdgcn_global_load_lds(
        (const __attribute__((address_space(1))) void*)g,
        (__attribute__((address_space(3))) void*)l, 16, 0, 0);
}

// wave reduce (64 lanes), op 0=sum 1=max
__device__ __forceinline__ float wave_reduce(float v, int op) {
    #pragma unroll
    for (int off = 32; off > 0; off >>= 1) {
        float o = __shfl_xor(v, off, 64);
        v = op ? fmaxf(v, o) : v + o;
    }
    return v;
}

// block-wide reduce (256 thr): wave shuffle + 4-slot LDS. op: 0=sum, 1=max.
__device__ __forceinline__ float block_reduce(float v, float* red4, int op) {
    v = wave_reduce(v, op);
    int w = threadIdx.x >> 6;
    if ((threadIdx.x & 63) == 0) red4[w] = v;
    __syncthreads();
    float r = op ? fmaxf(fmaxf(red4[0], red4[1]), fmaxf(red4[2], red4[3]))
                 : (red4[0] + red4[1] + red4[2] + red4[3]);
    __syncthreads();
    return r;
}

// ---------------------------------------------------------------------------
// Patchify: x (B,1,224,224) -> bf16 A[6272][256], A[b*196+q][pr*16+pc].
__global__ __launch_bounds__(256) void patchify_kernel(
        const float* __restrict__ x, unsigned short* __restrict__ Ab) {
    int pi = blockIdx.x;                 // 0..6271
    int b = pi / 196, q = pi % 196;
    int i = q / 14, j = q % 14;
    int e = threadIdx.x, pr = e >> 4, pc = e & 15;
    float v = x[((size_t)(b * 224 + i * 16 + pr)) * 224 + j * 16 + pc];
    Ab[(size_t)pi * 256 + e] = f2bf(v);
}

// cls token rows of h0
__global__ __launch_bounds__(256) void cls_pos_kernel(
        const float* __restrict__ cls, const float* __restrict__ pos,
        float* __restrict__ h0) {
    int b = blockIdx.x, e = threadIdx.x;
    h0[(size_t)(b * S) * E + e] = cls[e] + pos[e];
}

// fp32 -> bf16, 4 elems/thread
__global__ __launch_bounds__(256) void convert_kernel(
        const float* __restrict__ src, unsigned short* __restrict__ dst) {
    int i4 = (blockIdx.x * 256 + threadIdx.x) * 4;
    float4 v = *(const float4*)(src + i4);
    ushort4 o;
    o.x = f2bf(v.x); o.y = f2bf(v.y); o.z = f2bf(v.z); o.w = f2bf(v.w);
    *(ushort4*)(dst + i4) = o;
}

// ---------------------------------------------------------------------------
// rag stage 1: per-sample token means. grid 32, 256 thr, coalesced.
__global__ __launch_bounds__(256) void means_kernel(
        const float* __restrict__ h0, float* __restrict__ M) {
    int b = blockIdx.x, e = threadIdx.x;
    float s = 0.f;
    for (int t = 0; t < S; t++) s += h0[((size_t)(b * S + t)) * E + e];
    M[b * E + e] = s * (1.f / (float)S);
}

// rag stage 2: U_x[t] = Wk_x.T @ M[t] (coalesced Wk cols, uniform M scalars),
// c_x[t] = bk_x . M[t]. grid 32 (t), 256 thr.
__global__ __launch_bounds__(256) void uvec_kernel(
        const float* __restrict__ M,
        const float* __restrict__ Wkl, const float* __restrict__ bkl,
        const float* __restrict__ Wkr, const float* __restrict__ bkr,
        const float* __restrict__ Wkt, const float* __restrict__ bkt,
        float* __restrict__ Ul, float* __restrict__ Ur, float* __restrict__ Ut,
        float* __restrict__ cl, float* __restrict__ cr, float* __restrict__ ct) {
    __shared__ float red4[4];
    int t = blockIdx.x, e = threadIdx.x;
    const float* mt = M + t * E;
    float a0 = 0.f, a1 = 0.f, a2 = 0.f;
    for (int i = 0; i < 256; i++) {
        float mi = mt[i];                       // wave-uniform -> s_load
        a0 += Wkl[(size_t)i * 256 + e] * mi;
        a1 += Wkr[(size_t)i * 256 + e] * mi;
        a2 += Wkt[(size_t)i * 256 + e] * mi;
    }
    Ul[t * E + e] = a0; Ur[t * E + e] = a1; Ut[t * E + e] = a2;
    float me = mt[e];
    float c0 = block_reduce(bkl[e] * me, red4, 0);
    float c1 = block_reduce(bkr[e] * me, red4, 0);
    float c2 = block_reduce(bkt[e] * me, red4, 0);
    if (e == 0) { cl[t] = c0; cr[t] = c1; ct[t] = c2; }
}

// rag stage 3: scores+softmax+xbar+f for one (t, branch). grid 120, 256 thr.
__global__ __launch_bounds__(256) void rag_score_kernel(
        const float* __restrict__ h0, const float* __restrict__ M,
        const float* __restrict__ Ul, const float* __restrict__ Ur,
        const float* __restrict__ Ut,
        const float* __restrict__ cl, const float* __restrict__ cr,
        const float* __restrict__ ct,
        const float* __restrict__ Wvl, const float* __restrict__ bvl,
        const float* __restrict__ Wvr, const float* __restrict__ bvr,
        const float* __restrict__ Wvt, const float* __restrict__ bvt,
        float* __restrict__ fbuf) {
    int t = blockIdx.x >> 2, br = blockIdx.x & 3;
    const float* xsrc; const float* u; float c;
    const float* Wv; const float* bv; int dv, fo;
    if (br == 0)      { xsrc = h0 + (size_t)t * S * E;       u = Ul + (t+1)*E; c = cl[t+1]; Wv = Wvl; bv = bvl; dv = DVL; fo = 0; }
    else if (br == 1) { xsrc = h0 + (size_t)(t+1) * S * E;   u = Ut + t*E;     c = ct[t];   Wv = Wvt; bv = bvt; dv = DVT; fo = DVL; }
    else if (br == 2) { xsrc = h0 + (size_t)(t+1) * S * E;   u = Ut + (t+2)*E; c = ct[t+2]; Wv = Wvt; bv = bvt; dv = DVT; fo = DVL + DVT; }
    else              { xsrc = h0 + (size_t)(t+2) * S * E;   u = Ur + (t+1)*E; c = cr[t+1]; Wv = Wvr; bv = bvr; dv = DVR; fo = DVL + 2*DVT; }
    __shared__ float us[256], sc[200], xbar[256], red4[4];
    int tid = threadIdx.x, w = tid >> 6, lane = tid & 63;
    us[tid] = u[tid];
    __syncthreads();
    float4 u4 = *(float4*)&us[lane * 4];
    // scores: wave per token
    for (int s = w; s < S; s += 4) {
        float4 x4 = *(const float4*)&xsrc[(size_t)s * E + lane * 4];
        float p = x4.x*u4.x + x4.y*u4.y + x4.z*u4.z + x4.w*u4.w;
        p = wave_reduce(p, 0);
        if (lane == 0) sc[s] = (p + c) * 0.0625f;     // 1/sqrt(E)
    }
    __syncthreads();
    // softmax over S
    float v = (tid < S) ? sc[tid] : -1e30f;
    float mx = block_reduce(v, red4, 1);
    float ex = (tid < S) ? expf(v - mx) : 0.f;
    float dn = block_reduce(ex, red4, 0);
    if (tid < S) sc[tid] = ex / dn;
    __syncthreads();
    // xbar[e] = sum_s a[s] * xsrc[s][e]  (coalesced)
    float xb = 0.f;
    for (int s = 0; s < S; s++) xb += sc[s] * xsrc[(size_t)s * E + tid];
    xbar[tid] = xb;
    __syncthreads();
    // f[fo+d] = Wv[d] . xbar + bv[d]  (wave per output)
    float4 xb4 = *(float4*)&xbar[lane * 4];
    for (int d = w; d < dv; d += 4) {
        float4 w4 = *(const float4*)&Wv[(size_t)d * E + lane * 4];
        float p = w4.x*xb4.x + w4.y*xb4.y + w4.z*xb4.z + w4.w*xb4.w;
        p = wave_reduce(p, 0);
        if (lane == 0) fbuf[t * 256 + fo + d] = p + bv[d];
    }
}

// rag stage 4: outer product h1[t+1][s][:] = f[t][s] * M[t+1][:]
__global__ __launch_bounds__(256) void rag_outer_kernel(
        const float* __restrict__ fbuf, const float* __restrict__ M,
        float* __restrict__ h1) {
    int bid = blockIdx.x;                    // 0..30*197-1
    int t = bid / S, s = bid % S;
    float f = fbuf[t * 256 + s];             // uniform
    int e = threadIdx.x;
    h1[((size_t)((t + 1) * S + s)) * E + e] = f * M[(t + 1) * E + e];
}

// copy h0 samples 0 and 31 into h1
__global__ __launch_bounds__(256) void copy_edges(const float* __restrict__ h0,
                                                  float* __restrict__ h1) {
    int i = blockIdx.x * 256 + threadIdx.x;
    int n = S * E;
    if (i < n) h1[i] = h0[i];
    else if (i < 2 * n) {
        int j = i - n;
        size_t o = (size_t)31 * S * E + j;
        h1[o] = h0[o];
    }
}

// ---------------------------------------------------------------------------
// LayerNorm over E=256: wave per token, float4, shuffle-only (no barriers).
// grid = MS/4 blocks.
__global__ __launch_bounds__(256) void ln_kernel(const float* __restrict__ in,
                                                 unsigned short* __restrict__ out,
                                                 const float* __restrict__ g,
                                                 const float* __restrict__ b) {
    int w = threadIdx.x >> 6, lane = threadIdx.x & 63;
    int tok = blockIdx.x * 4 + w;
    const float* row = in + (size_t)tok * E;
    float4 v = *(const float4*)&row[lane * 4];
    float mean = wave_reduce(v.x + v.y + v.z + v.w, 0) * (1.f / 256.f);
    float dx = v.x - mean, dy = v.y - mean, dz = v.z - mean, dw = v.w - mean;
    float var = wave_reduce(dx*dx + dy*dy + dz*dz + dw*dw, 0) * (1.f / 256.f);
    float inv = rsqrtf(var + 1e-5f);
    float4 gg = *(const float4*)&g[lane * 4];
    float4 bb = *(const float4*)&b[lane * 4];
    ushort4 o;
    o.x = f2bf(dx * inv * gg.x + bb.x);
    o.y = f2bf(dy * inv * gg.y + bb.y);
    o.z = f2bf(dz * inv * gg.z + bb.z);
    o.w = f2bf(dw * inv * gg.w + bb.w);
    *(ushort4*)&out[(size_t)tok * E + lane * 4] = o;
}

// ---------------------------------------------------------------------------
// Per-layer weight conversion fp32 -> bf16 into staging buffer.
__global__ __launch_bounds__(256) void convert_w_kernel(
        const float* __restrict__ wqkv, const float* __restrict__ wo,
        const float* __restrict__ w1, const float* __restrict__ w2,
        unsigned short* __restrict__ out) {
    int idx = blockIdx.x * 256 + threadIdx.x;       // 0..458751
    int i4 = idx * 4;
    const float* src;
    if (i4 < 196608)       src = wqkv + i4;
    else if (i4 < 262144)  src = wo + (i4 - 196608);
    else if (i4 < 1048576) src = w1 + (i4 - 262144);
    else                   src = w2 + (i4 - 1048576);
    float4 v = *(const float4*)src;
    ushort4 o;
    o.x = f2bf(v.x); o.y = f2bf(v.y); o.z = f2bf(v.z); o.w = f2bf(v.w);
    *(ushort4*)(out + i4) = o;
}

// ---------------------------------------------------------------------------
// bf16 MFMA GEMM, 128x128 tile, BK=64, global_load_lds staging, XOR-swizzled
// unpadded LDS (granule col ^= row&7) -> conflict-free staging AND ds_read.
// MODE 0: fp32 store (+bias) | MODE 2: gelu -> bf16
template <int MODE>
__global__ __launch_bounds__(256) void mfma_gemm(
        const unsigned short* __restrict__ A, int lda,
        const unsigned short* __restrict__ W, int ldw,
        const float* __restrict__ bias,
        void* __restrict__ Cv, int ldc, int K) {
    __shared__ unsigned short As[128 * 64];
    __shared__ unsigned short Bs[128 * 64];
    const int m0 = blockIdx.y * 128, n0 = blockIdx.x * 128;
    const int tid = threadIdx.x, wave = tid >> 6, lane = tid & 63;
    const int wm = (wave >> 1) * 64, wn = (wave & 1) * 64;
    const int lr = lane & 15, kg = lane >> 4;
    const int srow = wave * 32 + (lane >> 3);           // +q*8
    const int scol = ((lane & 7) ^ (lane >> 3)) * 8;    // swizzled granule col (elems)
    f32x4 acc[4][4] = {};
    for (int k0 = 0; k0 < K; k0 += 64) {
        #pragma unroll
        for (int q = 0; q < 4; q++) {
            gload_lds16(&A[(size_t)(m0 + srow + q * 8) * lda + k0 + scol],
                        &As[(wave * 4 + q) * 512]);
            gload_lds16(&W[(size_t)(n0 + srow + q * 8) * ldw + k0 + scol],
                        &Bs[(wave * 4 + q) * 512]);
        }
        __syncthreads();
        #pragma unroll
        for (int h = 0; h < 2; h++) {
            const int sw = ((h * 4 + kg) ^ (lr & 7)) * 8;
            short8 af[4], bfr[4];
            #pragma unroll
            for (int i = 0; i < 4; i++) af[i]  = *(short8*)&As[(wm + i * 16 + lr) * 64 + sw];
            #pragma unroll
            for (int j = 0; j < 4; j++) bfr[j] = *(short8*)&Bs[(wn + j * 16 + lr) * 64 + sw];
            #pragma unroll
            for (int i = 0; i < 4; i++)
                #pragma unroll
                for (int j = 0; j < 4; j++)
                    acc[i][j] = __builtin_amdgcn_mfma_f32_16x16x32_bf16(af[i], bfr[j], acc[i][j], 0, 0, 0);
        }
        __syncthreads();
    }
    #pragma unroll
    for (int j = 0; j < 4; j++) {
        int n = n0 + wn + j * 16 + lr;
        float bv = bias ? bias[n] : 0.f;
        #pragma unroll
        for (int i = 0; i < 4; i++) {
            #pragma unroll
            for (int r = 0; r < 4; r++) {
                size_t m = (size_t)(m0 + wm + i * 16 + kg * 4 + r);
                float v = acc[i][j][r] + bv;
                if (MODE == 0) ((float*)Cv)[m * ldc + n] = v;
                if (MODE == 2) {
                    v = 0.5f * v * (1.f + erff(v * 0.70710678118654752f));
                    ((unsigned short*)Cv)[m * ldc + n] = f2bf(v);
                }
            }
        }
    }
}

// ---------------------------------------------------------------------------
// bf16 MFMA GEMM, 128x64 tile, BK=64, same staging/swizzle. 4 waves x (32x64).
// MODE 1: fp32 += (+bias) | MODE 3: patch-embed epilogue (token remap + pos)
template <int MODE>
__global__ __launch_bounds__(256) void mfma_gemm64(
        const unsigned short* __restrict__ A, int lda,
        const unsigned short* __restrict__ W, int ldw,
        const float* __restrict__ bias,
        void* __restrict__ Cv, int ldc, int K,
        const float* __restrict__ pos) {
    __shared__ unsigned short As[128 * 64];
    __shared__ unsigned short Bs[64 * 64];
    const int m0 = blockIdx.y * 128, n0 = blockIdx.x * 64;
    const int tid = threadIdx.x, wave = tid >> 6, lane = tid & 63;
    const int wm = wave * 32;
    const int lr = lane & 15, kg = lane >> 4;
    const int srow = wave * 32 + (lane >> 3);
    const int brow = wave * 16 + (lane >> 3);
    const int scol = ((lane & 7) ^ (lane >> 3)) * 8;
    f32x4 acc[2][4] = {};
    for (int k0 = 0; k0 < K; k0 += 64) {
        #pragma unroll
        for (int q = 0; q < 4; q++)
            gload_lds16(&A[(size_t)(m0 + srow + q * 8) * lda + k0 + scol],
                        &As[(wave * 4 + q) * 512]);
        #pragma unroll
        for (int q = 0; q < 2; q++)
            gload_lds16(&W[(size_t)(n0 + brow + q * 8) * ldw + k0 + scol],
                        &Bs[(wave * 2 + q) * 512]);
        __syncthreads();
        #pragma unroll
        for (int h = 0; h < 2; h++) {
            const int sw = ((h * 4 + kg) ^ (lr & 7)) * 8;
            short8 af[2], bfr[4];
            #pragma unroll
            for (int i = 0; i < 2; i++) af[i]  = *(short8*)&As[(wm + i * 16 + lr) * 64 + sw];
            #pragma unroll
            for (int j = 0; j < 4; j++) bfr[j] = *(short8*)&Bs[(j * 16 + lr) * 64 + sw];
            #pragma unroll
            for (int i = 0; i < 2; i++)
                #pragma unroll
                for (int j = 0; j < 4; j++)
                    acc[i][j] = __builtin_amdgcn_mfma_f32_16x16x32_bf16(af[i], bfr[j], acc[i][j], 0, 0, 0);
        }
        __syncthreads();
    }
    #pragma unroll
    for (int j = 0; j < 4; j++) {
        int n = n0 + j * 16 + lr;
        float bv = bias ? bias[n] : 0.f;
        #pragma unroll
        for (int i = 0; i < 2; i++) {
            #pragma unroll
            for (int r = 0; r < 4; r++) {
                int m = m0 + wm + i * 16 + kg * 4 + r;
                float v = acc[i][j][r] + bv;
                if (MODE == 1) ((float*)Cv)[(size_t)m * ldc + n] += v;
                if (MODE == 3) {
                    int b = m / 196, s = m - b * 196 + 1;   // token remap
                    ((float*)Cv)[((size_t)(b * S + s)) * E + n] = v + pos[(size_t)s * E + n];
                }
            }
        }
    }
}

// ---------------------------------------------------------------------------
// Attention: one block per (sample, head). K/V staged in LDS; online softmax.
__global__ __launch_bounds__(256) void attn_kernel(const float* __restrict__ qkv,
                                                   unsigned short* __restrict__ o) {
    int bh = blockIdx.x;
    int b = bh / Hn, hh = bh % Hn;
    __shared__ float Ks[S][HD];
    __shared__ float Vs[S][HD];
    int tid = threadIdx.x;
    for (int i = tid; i < S * HD; i += 256) {
        int s = i / HD, d = i % HD;
        size_t base = ((size_t)(b * S + s)) * 768 + hh * HD + d;
        Ks[s][d] = qkv[base + 256];
        Vs[s][d] = qkv[base + 512];
    }
    __syncthreads();
    int s = tid;
    if (s < S) {
        float q[HD];
        const float* qp = qkv + ((size_t)(b * S + s)) * 768 + hh * HD;
        #pragma unroll
        for (int d = 0; d < HD; d++) q[d] = qp[d] * 0.25f;   // 1/sqrt(HD)
        float m = -1e30f, l = 0.f, acc[HD] = {};
        for (int k = 0; k < S; k++) {
            float sc = 0.f;
            #pragma unroll
            for (int d = 0; d < HD; d++) sc += q[d] * Ks[k][d];
            float mn = fmaxf(m, sc);
            float corr = expf(m - mn);
            float p = expf(sc - mn);
            l = l * corr + p;
            #pragma unroll
            for (int d = 0; d < HD; d++) acc[d] = acc[d] * corr + p * Vs[k][d];
            m = mn;
        }
        float inv = 1.f / l;
        unsigned short* op = o + ((size_t)(b * S + s)) * E + hh * HD;
        #pragma unroll
        for (int d = 0; d < HD; d++) op[d] = f2bf(acc[d] * inv);
    }
}

// ---------------------------------------------------------------------------
// Final LN on cls token + head GEMM. One block per sample.
__global__ __launch_bounds__(256) void head_kernel(
        const float* __restrict__ h, const float* __restrict__ g,
        const float* __restrict__ bb, const float* __restrict__ Wh,
        const float* __restrict__ bh, float* __restrict__ out) {
    __shared__ float red4[4];
    __shared__ float xs[256];
    int b = blockIdx.x, e = threadIdx.x;
    float v = h[((size_t)(b * S)) * E + e];
    float mean = block_reduce(v, red4, 0) * (1.f / 256.f);
    float d = v - mean;
    float var = block_reduce(d * d, red4, 0) * (1.f / 256.f);
    float xn = d * rsqrtf(var + 1e-5f) * g[e] + bb[e];
    xs[e] = xn;
    __syncthreads();
    for (int n = 0; n < 8; n++) {
        float s = block_reduce(xs[e] * Wh[(size_t)n * 256 + e], red4, 0);
        if (e == 0) out[b * 8 + n] = s + bh[n];
    }
}

// ---------------------------------------------------------------------------
extern "C" void kernel_launch(void* const* d_in, const int* in_sizes, int n_in,
                              void* d_out, int out_size, void* d_ws, size_t ws_size,
                              hipStream_t stream) {
    const float* x      = (const float*)d_in[0];
    const float* W_patch= (const float*)d_in[1];
    const float* b_patch= (const float*)d_in[2];
    const float* cls_tok= (const float*)d_in[3];
    const float* pos_emb= (const float*)d_in[4];
    const float* Wkl = (const float*)d_in[5];   const float* bkl = (const float*)d_in[6];
    const float* Wvl = (const float*)d_in[7];   const float* bvl = (const float*)d_in[8];
    const float* Wkr = (const float*)d_in[9];   const float* bkr = (const float*)d_in[10];
    const float* Wvr = (const float*)d_in[11];  const float* bvr = (const float*)d_in[12];
    const float* Wkt = (const float*)d_in[13];  const float* bkt = (const float*)d_in[14];
    const float* Wvt = (const float*)d_in[15];  const float* bvt = (const float*)d_in[16];
    const float* ln1_g = (const float*)d_in[17]; const float* ln1_b = (const float*)d_in[18];
    const float* Wqkv  = (const float*)d_in[19]; const float* bqkv  = (const float*)d_in[20];
    const float* Wo    = (const float*)d_in[21]; const float* bo    = (const float*)d_in[22];
    const float* ln2_g = (const float*)d_in[23]; const float* ln2_b = (const float*)d_in[24];
    const float* W1 = (const float*)d_in[25];   const float* b1 = (const float*)d_in[26];
    const float* W2 = (const float*)d_in[27];   const float* b2 = (const float*)d_in[28];
    const float* lnf_g = (const float*)d_in[29]; const float* lnf_b = (const float*)d_in[30];
    const float* W_head = (const float*)d_in[31]; const float* b_head = (const float*)d_in[32];

    // Workspace layout (bytes): total 82,313,216 B
    char* p = (char*)d_ws;
    float* h0 = (float*)p;                   p += (size_t)MP * 256 * 4;
    float* h1 = (float*)p;                   p += (size_t)MP * 256 * 4;
    float* qk = (float*)p;                   p += (size_t)MP * 768 * 4;
    unsigned short* xnb = (unsigned short*)p; p += (size_t)MP * 256 * 2;
    unsigned short* ob  = (unsigned short*)p; p += (size_t)MP * 256 * 2;
    unsigned short* ff  = (unsigned short*)p; p += (size_t)MP * 3072 * 2;
    unsigned short* wb  = (unsigned short*)p;
    unsigned short* wqkv_b = wb;             // 196608
    unsigned short* wo_b   = wb + 196608;    // 65536
    unsigned short* w1_b   = wb + 262144;    // 786432
    unsigned short* w2_b   = wb + 1048576;   // 786432

    // rag scratch lives inside qk (unused until the layer loop)
    float* M    = qk;                 // 32*256
    float* Ul   = qk + 8192;          // 32*256
    float* Ur   = qk + 2 * 8192;
    float* Ut   = qk + 3 * 8192;
    float* cl   = qk + 4 * 8192;      // 32
    float* cr   = cl + 32;
    float* ct   = cl + 64;
    float* fbuf = cl + 96;            // 30*256

    // ---- patch embedding as MFMA GEMM ----
    convert_kernel<<<64, 256, 0, stream>>>(W_patch, wqkv_b);   // Wp bf16 (wb free pre-loop)
    patchify_kernel<<<NPAT, 256, 0, stream>>>(x, xnb);
    cls_pos_kernel<<<Bz, 256, 0, stream>>>(cls_tok, pos_emb, h0);
    mfma_gemm64<3><<<dim3(4, NPAT / 128), 256, 0, stream>>>(
        xnb, 256, wqkv_b, 256, b_patch, h0, 256, 256, pos_emb);

    // ---- rag mixer (parallelized, fp32) ----
    means_kernel<<<Bz, 256, 0, stream>>>(h0, M);
    uvec_kernel<<<Bz, 256, 0, stream>>>(M, Wkl, bkl, Wkr, bkr, Wkt, bkt,
                                        Ul, Ur, Ut, cl, cr, ct);
    rag_score_kernel<<<(Bz - 2) * 4, 256, 0, stream>>>(
        h0, M, Ul, Ur, Ut, cl, cr, ct, Wvl, bvl, Wvr, bvr, Wvt, bvt, fbuf);
    rag_outer_kernel<<<(Bz - 2) * S, 256, 0, stream>>>(fbuf, M, h1);
    copy_edges<<<(2 * S * E + 255) / 256, 256, 0, stream>>>(h0, h1);

    const int gy = MP / 128;   // 50 M-tiles
    for (int l = 0; l < Ln; l++) {
        convert_w_kernel<<<1792, 256, 0, stream>>>(
            Wqkv + (size_t)l * 768 * 256, Wo + (size_t)l * 256 * 256,
            W1 + (size_t)l * Fd * 256, W2 + (size_t)l * 256 * Fd, wb);
        ln_kernel<<<MS / 4, 256, 0, stream>>>(h1, xnb, ln1_g + l * E, ln1_b + l * E);
        mfma_gemm<0><<<dim3(6, gy), 256, 0, stream>>>(
            xnb, 256, wqkv_b, 256, bqkv + l * 768, qk, 768, 256);
        attn_kernel<<<Bz * Hn, 256, 0, stream>>>(qk, ob);
        mfma_gemm64<1><<<dim3(4, gy), 256, 0, stream>>>(
            ob, 256, wo_b, 256, bo + l * 256, h1, 256, 256, nullptr);
        ln_kernel<<<MS / 4, 256, 0, stream>>>(h1, xnb, ln2_g + l * E, ln2_b + l * E);
        mfma_gemm<2><<<dim3(24, gy), 256, 0, stream>>>(
            xnb, 256, w1_b, 256, b1 + l * Fd, ff, 3072, 256);
        mfma_gemm64<1><<<dim3(4, gy), 256, 0, stream>>>(
            ff, 3072, w2_b, 3072, b2 + l * 256, h1, 256, 3072, nullptr);
    }
    head_kernel<<<Bz, 256, 0, stream>>>(h1, lnf_g, lnf_b, W_head, b_head, (float*)d_out);
}

// Round 5
// 1856.789 us; speedup vs baseline: 5.6233x; 1.3087x over previous
//
#include <hip/hip_runtime.h>
#include <hip/hip_bf16.h>
#include <math.h>

// Problem constants
constexpr int Bz  = 32;
constexpr int S   = 197;
constexpr int E   = 256;
constexpr int Hn  = 16;
constexpr int HD  = 16;
constexpr int Fd  = 3072;
constexpr int Ln  = 12;
constexpr int MS  = Bz * S;         // 6304 tokens
constexpr int MP  = 6400;           // padded to 50 * 128 for MFMA GEMM tiles
constexpr int NPAT = 6272;          // 32*196 patches = 49*128 exactly
constexpr int DVL = 50, DVR = 49, DVT = 49;

typedef __attribute__((ext_vector_type(8))) short short8;   // 8 bf16 = 4 VGPRs
typedef __attribute__((ext_vector_type(4))) short short4v;
typedef __attribute__((ext_vector_type(4))) float f32x4;

__device__ __forceinline__ unsigned short f2bf(float f) {
    unsigned int u = __float_as_uint(f);
    u = (u + 0x7FFFu + ((u >> 16) & 1u)) >> 16;             // RNE
    return (unsigned short)u;
}

// async global->LDS, 16 B per lane. LDS dest is wave-uniform base + lane*16.
__device__ __forceinline__ void gload_lds16(const void* g, void* l) {
    __builtin_amdgcn_global_load_lds(
        (const __attribute__((address_space(1))) void*)g,
        (__attribute__((address_space(3))) void*)l, 16, 0, 0);
}

// wave reduce (64 lanes), op 0=sum 1=max
__device__ __forceinline__ float wave_reduce(float v, int op) {
    #pragma unroll
    for (int off = 32; off > 0; off >>= 1) {
        float o = __shfl_xor(v, off, 64);
        v = op ? fmaxf(v, o) : v + o;
    }
    return v;
}

// block-wide reduce (256 thr): wave shuffle + 4-slot LDS. op: 0=sum, 1=max.
__device__ __forceinline__ float block_reduce(float v, float* red4, int op) {
    v = wave_reduce(v, op);
    int w = threadIdx.x >> 6;
    if ((threadIdx.x & 63) == 0) red4[w] = v;
    __syncthreads();
    float r = op ? fmaxf(fmaxf(red4[0], red4[1]), fmaxf(red4[2], red4[3]))
                 : (red4[0] + red4[1] + red4[2] + red4[3]);
    __syncthreads();
    return r;
}

// ---------------------------------------------------------------------------
// Patchify: x (B,1,224,224) -> bf16 A[6272][256], A[b*196+q][pr*16+pc].
__global__ __launch_bounds__(256) void patchify_kernel(
        const float* __restrict__ x, unsigned short* __restrict__ Ab) {
    int pi = blockIdx.x;                 // 0..6271
    int b = pi / 196, q = pi % 196;
    int i = q / 14, j = q % 14;
    int e = threadIdx.x, pr = e >> 4, pc = e & 15;
    float v = x[((size_t)(b * 224 + i * 16 + pr)) * 224 + j * 16 + pc];
    Ab[(size_t)pi * 256 + e] = f2bf(v);
}

// cls token rows of h0
__global__ __launch_bounds__(256) void cls_pos_kernel(
        const float* __restrict__ cls, const float* __restrict__ pos,
        float* __restrict__ h0) {
    int b = blockIdx.x, e = threadIdx.x;
    h0[(size_t)(b * S) * E + e] = cls[e] + pos[e];
}

// fp32 -> bf16, 4 elems/thread
__global__ __launch_bounds__(256) void convert_kernel(
        const float* __restrict__ src, unsigned short* __restrict__ dst) {
    int i4 = (blockIdx.x * 256 + threadIdx.x) * 4;
    float4 v = *(const float4*)(src + i4);
    ushort4 o;
    o.x = f2bf(v.x); o.y = f2bf(v.y); o.z = f2bf(v.z); o.w = f2bf(v.w);
    *(ushort4*)(dst + i4) = o;
}

// ---------------------------------------------------------------------------
// rag stage 1: per-sample token means. grid 32, 256 thr, coalesced.
__global__ __launch_bounds__(256) void means_kernel(
        const float* __restrict__ h0, float* __restrict__ M) {
    int b = blockIdx.x, e = threadIdx.x;
    float s = 0.f;
    for (int t = 0; t < S; t++) s += h0[((size_t)(b * S + t)) * E + e];
    M[b * E + e] = s * (1.f / (float)S);
}

// rag stage 2: U_x[t] = Wk_x.T @ M[t], c_x[t] = bk_x . M[t]. grid 32.
__global__ __launch_bounds__(256) void uvec_kernel(
        const float* __restrict__ M,
        const float* __restrict__ Wkl, const float* __restrict__ bkl,
        const float* __restrict__ Wkr, const float* __restrict__ bkr,
        const float* __restrict__ Wkt, const float* __restrict__ bkt,
        float* __restrict__ Ul, float* __restrict__ Ur, float* __restrict__ Ut,
        float* __restrict__ cl, float* __restrict__ cr, float* __restrict__ ct) {
    __shared__ float red4[4];
    int t = blockIdx.x, e = threadIdx.x;
    const float* mt = M + t * E;
    float a0 = 0.f, a1 = 0.f, a2 = 0.f;
    for (int i = 0; i < 256; i++) {
        float mi = mt[i];                       // wave-uniform -> s_load
        a0 += Wkl[(size_t)i * 256 + e] * mi;
        a1 += Wkr[(size_t)i * 256 + e] * mi;
        a2 += Wkt[(size_t)i * 256 + e] * mi;
    }
    Ul[t * E + e] = a0; Ur[t * E + e] = a1; Ut[t * E + e] = a2;
    float me = mt[e];
    float c0 = block_reduce(bkl[e] * me, red4, 0);
    float c1 = block_reduce(bkr[e] * me, red4, 0);
    float c2 = block_reduce(bkt[e] * me, red4, 0);
    if (e == 0) { cl[t] = c0; cr[t] = c1; ct[t] = c2; }
}

// rag stage 3: scores+softmax+xbar+f for one (t, branch). grid 120, 256 thr.
__global__ __launch_bounds__(256) void rag_score_kernel(
        const float* __restrict__ h0, const float* __restrict__ M,
        const float* __restrict__ Ul, const float* __restrict__ Ur,
        const float* __restrict__ Ut,
        const float* __restrict__ cl, const float* __restrict__ cr,
        const float* __restrict__ ct,
        const float* __restrict__ Wvl, const float* __restrict__ bvl,
        const float* __restrict__ Wvr, const float* __restrict__ bvr,
        const float* __restrict__ Wvt, const float* __restrict__ bvt,
        float* __restrict__ fbuf) {
    int t = blockIdx.x >> 2, br = blockIdx.x & 3;
    const float* xsrc; const float* u; float c;
    const float* Wv; const float* bv; int dv, fo;
    if (br == 0)      { xsrc = h0 + (size_t)t * S * E;       u = Ul + (t+1)*E; c = cl[t+1]; Wv = Wvl; bv = bvl; dv = DVL; fo = 0; }
    else if (br == 1) { xsrc = h0 + (size_t)(t+1) * S * E;   u = Ut + t*E;     c = ct[t];   Wv = Wvt; bv = bvt; dv = DVT; fo = DVL; }
    else if (br == 2) { xsrc = h0 + (size_t)(t+1) * S * E;   u = Ut + (t+2)*E; c = ct[t+2]; Wv = Wvt; bv = bvt; dv = DVT; fo = DVL + DVT; }
    else              { xsrc = h0 + (size_t)(t+2) * S * E;   u = Ur + (t+1)*E; c = cr[t+1]; Wv = Wvr; bv = bvr; dv = DVR; fo = DVL + 2*DVT; }
    __shared__ float us[256], sc[200], xbar[256], red4[4];
    int tid = threadIdx.x, w = tid >> 6, lane = tid & 63;
    us[tid] = u[tid];
    __syncthreads();
    float4 u4 = *(float4*)&us[lane * 4];
    for (int s = w; s < S; s += 4) {
        float4 x4 = *(const float4*)&xsrc[(size_t)s * E + lane * 4];
        float p = x4.x*u4.x + x4.y*u4.y + x4.z*u4.z + x4.w*u4.w;
        p = wave_reduce(p, 0);
        if (lane == 0) sc[s] = (p + c) * 0.0625f;     // 1/sqrt(E)
    }
    __syncthreads();
    float v = (tid < S) ? sc[tid] : -1e30f;
    float mx = block_reduce(v, red4, 1);
    float ex = (tid < S) ? expf(v - mx) : 0.f;
    float dn = block_reduce(ex, red4, 0);
    if (tid < S) sc[tid] = ex / dn;
    __syncthreads();
    float xb = 0.f;
    for (int s = 0; s < S; s++) xb += sc[s] * xsrc[(size_t)s * E + tid];
    xbar[tid] = xb;
    __syncthreads();
    float4 xb4 = *(float4*)&xbar[lane * 4];
    for (int d = w; d < dv; d += 4) {
        float4 w4 = *(const float4*)&Wv[(size_t)d * E + lane * 4];
        float p = w4.x*xb4.x + w4.y*xb4.y + w4.z*xb4.z + w4.w*xb4.w;
        p = wave_reduce(p, 0);
        if (lane == 0) fbuf[t * 256 + fo + d] = p + bv[d];
    }
}

// rag stage 4: outer product h1[t+1][s][:] = f[t][s] * M[t+1][:]
__global__ __launch_bounds__(256) void rag_outer_kernel(
        const float* __restrict__ fbuf, const float* __restrict__ M,
        float* __restrict__ h1) {
    int bid = blockIdx.x;                    // 0..30*197-1
    int t = bid / S, s = bid % S;
    float f = fbuf[t * 256 + s];             // uniform
    int e = threadIdx.x;
    h1[((size_t)((t + 1) * S + s)) * E + e] = f * M[(t + 1) * E + e];
}

// copy h0 samples 0 and 31 into h1
__global__ __launch_bounds__(256) void copy_edges(const float* __restrict__ h0,
                                                  float* __restrict__ h1) {
    int i = blockIdx.x * 256 + threadIdx.x;
    int n = S * E;
    if (i < n) h1[i] = h0[i];
    else if (i < 2 * n) {
        int j = i - n;
        size_t o = (size_t)31 * S * E + j;
        h1[o] = h0[o];
    }
}

// ---------------------------------------------------------------------------
// LayerNorm over E=256: wave per token, float4, shuffle-only. grid MS/4.
__global__ __launch_bounds__(256) void ln_kernel(const float* __restrict__ in,
                                                 unsigned short* __restrict__ out,
                                                 const float* __restrict__ g,
                                                 const float* __restrict__ b) {
    int w = threadIdx.x >> 6, lane = threadIdx.x & 63;
    int tok = blockIdx.x * 4 + w;
    const float* row = in + (size_t)tok * E;
    float4 v = *(const float4*)&row[lane * 4];
    float mean = wave_reduce(v.x + v.y + v.z + v.w, 0) * (1.f / 256.f);
    float dx = v.x - mean, dy = v.y - mean, dz = v.z - mean, dw = v.w - mean;
    float var = wave_reduce(dx*dx + dy*dy + dz*dz + dw*dw, 0) * (1.f / 256.f);
    float inv = rsqrtf(var + 1e-5f);
    float4 gg = *(const float4*)&g[lane * 4];
    float4 bb = *(const float4*)&b[lane * 4];
    ushort4 o;
    o.x = f2bf(dx * inv * gg.x + bb.x);
    o.y = f2bf(dy * inv * gg.y + bb.y);
    o.z = f2bf(dz * inv * gg.z + bb.z);
    o.w = f2bf(dw * inv * gg.w + bb.w);
    *(ushort4*)&out[(size_t)tok * E + lane * 4] = o;
}

// ---------------------------------------------------------------------------
// Per-layer weight conversion fp32 -> bf16 into staging buffer.
__global__ __launch_bounds__(256) void convert_w_kernel(
        const float* __restrict__ wqkv, const float* __restrict__ wo,
        const float* __restrict__ w1, const float* __restrict__ w2,
        unsigned short* __restrict__ out) {
    int idx = blockIdx.x * 256 + threadIdx.x;       // 0..458751
    int i4 = idx * 4;
    const float* src;
    if (i4 < 196608)       src = wqkv + i4;
    else if (i4 < 262144)  src = wo + (i4 - 196608);
    else if (i4 < 1048576) src = w1 + (i4 - 262144);
    else                   src = w2 + (i4 - 1048576);
    float4 v = *(const float4*)src;
    ushort4 o;
    o.x = f2bf(v.x); o.y = f2bf(v.y); o.z = f2bf(v.z); o.w = f2bf(v.w);
    *(ushort4*)(out + i4) = o;
}

// ---------------------------------------------------------------------------
// bf16 MFMA GEMM, 128x128 tile, BK=64, global_load_lds staging, XOR-swizzled
// LDS. MODE 0: fp32 store (+bias) | MODE 2: gelu -> bf16 | MODE 4: bf16 store
template <int MODE>
__global__ __launch_bounds__(256) void mfma_gemm(
        const unsigned short* __restrict__ A, int lda,
        const unsigned short* __restrict__ W, int ldw,
        const float* __restrict__ bias,
        void* __restrict__ Cv, int ldc, int K) {
    __shared__ unsigned short As[128 * 64];
    __shared__ unsigned short Bs[128 * 64];
    const int m0 = blockIdx.y * 128, n0 = blockIdx.x * 128;
    const int tid = threadIdx.x, wave = tid >> 6, lane = tid & 63;
    const int wm = (wave >> 1) * 64, wn = (wave & 1) * 64;
    const int lr = lane & 15, kg = lane >> 4;
    const int srow = wave * 32 + (lane >> 3);           // +q*8
    const int scol = ((lane & 7) ^ (lane >> 3)) * 8;    // swizzled granule col
    f32x4 acc[4][4] = {};
    for (int k0 = 0; k0 < K; k0 += 64) {
        #pragma unroll
        for (int q = 0; q < 4; q++) {
            gload_lds16(&A[(size_t)(m0 + srow + q * 8) * lda + k0 + scol],
                        &As[(wave * 4 + q) * 512]);
            gload_lds16(&W[(size_t)(n0 + srow + q * 8) * ldw + k0 + scol],
                        &Bs[(wave * 4 + q) * 512]);
        }
        __syncthreads();
        #pragma unroll
        for (int h = 0; h < 2; h++) {
            const int sw = ((h * 4 + kg) ^ (lr & 7)) * 8;
            short8 af[4], bfr[4];
            #pragma unroll
            for (int i = 0; i < 4; i++) af[i]  = *(short8*)&As[(wm + i * 16 + lr) * 64 + sw];
            #pragma unroll
            for (int j = 0; j < 4; j++) bfr[j] = *(short8*)&Bs[(wn + j * 16 + lr) * 64 + sw];
            #pragma unroll
            for (int i = 0; i < 4; i++)
                #pragma unroll
                for (int j = 0; j < 4; j++)
                    acc[i][j] = __builtin_amdgcn_mfma_f32_16x16x32_bf16(af[i], bfr[j], acc[i][j], 0, 0, 0);
        }
        __syncthreads();
    }
    #pragma unroll
    for (int j = 0; j < 4; j++) {
        int n = n0 + wn + j * 16 + lr;
        float bv = bias ? bias[n] : 0.f;
        #pragma unroll
        for (int i = 0; i < 4; i++) {
            #pragma unroll
            for (int r = 0; r < 4; r++) {
                size_t m = (size_t)(m0 + wm + i * 16 + kg * 4 + r);
                float v = acc[i][j][r] + bv;
                if (MODE == 0) ((float*)Cv)[m * ldc + n] = v;
                if (MODE == 2) {
                    v = 0.5f * v * (1.f + erff(v * 0.70710678118654752f));
                    ((unsigned short*)Cv)[m * ldc + n] = f2bf(v);
                }
                if (MODE == 4) ((unsigned short*)Cv)[m * ldc + n] = f2bf(v);
            }
        }
    }
}

// ---------------------------------------------------------------------------
// bf16 MFMA GEMM, 128x64 tile, BK=64, same staging/swizzle. 4 waves x (32x64).
// MODE 1: fp32 += (+bias) | MODE 3: patch-embed epilogue (token remap + pos)
template <int MODE>
__global__ __launch_bounds__(256) void mfma_gemm64(
        const unsigned short* __restrict__ A, int lda,
        const unsigned short* __restrict__ W, int ldw,
        const float* __restrict__ bias,
        void* __restrict__ Cv, int ldc, int K,
        const float* __restrict__ pos) {
    __shared__ unsigned short As[128 * 64];
    __shared__ unsigned short Bs[64 * 64];
    const int m0 = blockIdx.y * 128, n0 = blockIdx.x * 64;
    const int tid = threadIdx.x, wave = tid >> 6, lane = tid & 63;
    const int wm = wave * 32;
    const int lr = lane & 15, kg = lane >> 4;
    const int srow = wave * 32 + (lane >> 3);
    const int brow = wave * 16 + (lane >> 3);
    const int scol = ((lane & 7) ^ (lane >> 3)) * 8;
    f32x4 acc[2][4] = {};
    for (int k0 = 0; k0 < K; k0 += 64) {
        #pragma unroll
        for (int q = 0; q < 4; q++)
            gload_lds16(&A[(size_t)(m0 + srow + q * 8) * lda + k0 + scol],
                        &As[(wave * 4 + q) * 512]);
        #pragma unroll
        for (int q = 0; q < 2; q++)
            gload_lds16(&W[(size_t)(n0 + brow + q * 8) * ldw + k0 + scol],
                        &Bs[(wave * 2 + q) * 512]);
        __syncthreads();
        #pragma unroll
        for (int h = 0; h < 2; h++) {
            const int sw = ((h * 4 + kg) ^ (lr & 7)) * 8;
            short8 af[2], bfr[4];
            #pragma unroll
            for (int i = 0; i < 2; i++) af[i]  = *(short8*)&As[(wm + i * 16 + lr) * 64 + sw];
            #pragma unroll
            for (int j = 0; j < 4; j++) bfr[j] = *(short8*)&Bs[(j * 16 + lr) * 64 + sw];
            #pragma unroll
            for (int i = 0; i < 2; i++)
                #pragma unroll
                for (int j = 0; j < 4; j++)
                    acc[i][j] = __builtin_amdgcn_mfma_f32_16x16x32_bf16(af[i], bfr[j], acc[i][j], 0, 0, 0);
        }
        __syncthreads();
    }
    #pragma unroll
    for (int j = 0; j < 4; j++) {
        int n = n0 + j * 16 + lr;
        float bv = bias ? bias[n] : 0.f;
        #pragma unroll
        for (int i = 0; i < 2; i++) {
            #pragma unroll
            for (int r = 0; r < 4; r++) {
                int m = m0 + wm + i * 16 + kg * 4 + r;
                float v = acc[i][j][r] + bv;
                if (MODE == 1) ((float*)Cv)[(size_t)m * ldc + n] += v;
                if (MODE == 3) {
                    int b = m / 196, s = m - b * 196 + 1;   // token remap
                    ((float*)Cv)[((size_t)(b * S + s)) * E + n] = v + pos[(size_t)s * E + n];
                }
            }
        }
    }
}

// ---------------------------------------------------------------------------
// MFMA flash attention. One block per (b,h); 4 waves, each takes Q-tiles
// round-robin. qkv bf16 [MS][768]; out bf16 [MS][256].
// Q,K staged [208][32] (d padded to 32 = one 16x16x32 k-step, zeros);
// V transposed [16][224]; P per-wave [16][224] (C->A layout round-trip).
__global__ __launch_bounds__(256) void attn_kernel(
        const unsigned short* __restrict__ qkv, unsigned short* __restrict__ o) {
    int b = blockIdx.x >> 4, hh = blockIdx.x & 15;
    __shared__ unsigned short Qs[208][32];
    __shared__ unsigned short Ks[208][32];
    __shared__ unsigned short Vt[16][224];
    __shared__ unsigned short Ps[4][16][224];
    int tid = threadIdx.x, wave = tid >> 6, lane = tid & 63;
    int lr = lane & 15, kg = lane >> 4;
    short8 z8 = {};
    if (tid < 208) {
        if (tid < 197) {
            size_t row = (size_t)(b * S + tid) * 768 + hh * 16;
            *(short8*)&Qs[tid][0] = *(const short8*)&qkv[row];
            *(short8*)&Qs[tid][8] = *(const short8*)&qkv[row + 8];
            *(short8*)&Ks[tid][0] = *(const short8*)&qkv[row + 256];
            *(short8*)&Ks[tid][8] = *(const short8*)&qkv[row + 264];
            union { short8 v8[2]; unsigned short u[16]; } vv;
            vv.v8[0] = *(const short8*)&qkv[row + 512];
            vv.v8[1] = *(const short8*)&qkv[row + 520];
            #pragma unroll
            for (int d = 0; d < 16; d++) Vt[d][tid] = vv.u[d];
        } else {
            *(short8*)&Qs[tid][0] = z8; *(short8*)&Qs[tid][8] = z8;
            *(short8*)&Ks[tid][0] = z8; *(short8*)&Ks[tid][8] = z8;
            #pragma unroll
            for (int d = 0; d < 16; d++) Vt[d][tid] = 0;
        }
        *(short8*)&Qs[tid][16] = z8; *(short8*)&Qs[tid][24] = z8;
        *(short8*)&Ks[tid][16] = z8; *(short8*)&Ks[tid][24] = z8;
    } else if (tid < 224) {
        #pragma unroll
        for (int d = 0; d < 16; d++) Vt[d][tid] = 0;
    }
    {   // zero P pad cols [208,224) of this wave's scratch
        short4v z4 = {};
        *(short4v*)&Ps[wave][lane >> 2][208 + (lane & 3) * 4] = z4;
    }
    __syncthreads();
    const f32x4 zf = {0.f, 0.f, 0.f, 0.f};
    for (int it = wave; it < 13; it += 4) {
        short8 qa = *(short8*)&Qs[it * 16 + lr][kg * 8];
        f32x4 sc[13];
        #pragma unroll
        for (int j = 0; j < 13; j++) {
            short8 kb = *(short8*)&Ks[j * 16 + lr][kg * 8];
            sc[j] = __builtin_amdgcn_mfma_f32_16x16x32_bf16(qa, kb, zf, 0, 0, 0);
        }
        float m[4] = {-1e30f, -1e30f, -1e30f, -1e30f};
        #pragma unroll
        for (int j = 0; j < 13; j++) {
            if (j * 16 + lr < 197) {
                #pragma unroll
                for (int r = 0; r < 4; r++) m[r] = fmaxf(m[r], sc[j][r]);
            }
        }
        #pragma unroll
        for (int off = 1; off < 16; off <<= 1)
            #pragma unroll
            for (int r = 0; r < 4; r++) m[r] = fmaxf(m[r], __shfl_xor(m[r], off, 64));
        float l[4] = {0.f, 0.f, 0.f, 0.f};
        #pragma unroll
        for (int j = 0; j < 13; j++) {
            bool valid = (j * 16 + lr) < 197;
            #pragma unroll
            for (int r = 0; r < 4; r++) {
                float p = valid ? __expf((sc[j][r] - m[r]) * 0.25f) : 0.f;
                l[r] += p;
                Ps[wave][kg * 4 + r][j * 16 + lr] = f2bf(p);
            }
        }
        #pragma unroll
        for (int off = 1; off < 16; off <<= 1)
            #pragma unroll
            for (int r = 0; r < 4; r++) l[r] += __shfl_xor(l[r], off, 64);
        f32x4 oa = zf;
        #pragma unroll
        for (int k0 = 0; k0 < 224; k0 += 32) {
            short8 pa = *(short8*)&Ps[wave][lr][k0 + kg * 8];
            short8 vb = *(short8*)&Vt[lr][k0 + kg * 8];
            oa = __builtin_amdgcn_mfma_f32_16x16x32_bf16(pa, vb, oa, 0, 0, 0);
        }
        #pragma unroll
        for (int r = 0; r < 4; r++) {
            int q = it * 16 + kg * 4 + r;
            if (q < 197)
                o[((size_t)(b * S + q)) * 256 + hh * 16 + lr] = f2bf(oa[r] / l[r]);
        }
    }
}

// ---------------------------------------------------------------------------
// Final LN on cls token + head GEMM. One block per sample.
__global__ __launch_bounds__(256) void head_kernel(
        const float* __restrict__ h, const float* __restrict__ g,
        const float* __restrict__ bb, const float* __restrict__ Wh,
        const float* __restrict__ bh, float* __restrict__ out) {
    __shared__ float red4[4];
    __shared__ float xs[256];
    int b = blockIdx.x, e = threadIdx.x;
    float v = h[((size_t)(b * S)) * E + e];
    float mean = block_reduce(v, red4, 0) * (1.f / 256.f);
    float d = v - mean;
    float var = block_reduce(d * d, red4, 0) * (1.f / 256.f);
    float xn = d * rsqrtf(var + 1e-5f) * g[e] + bb[e];
    xs[e] = xn;
    __syncthreads();
    for (int n = 0; n < 8; n++) {
        float s = block_reduce(xs[e] * Wh[(size_t)n * 256 + e], red4, 0);
        if (e == 0) out[b * 8 + n] = s + bh[n];
    }
}

// ---------------------------------------------------------------------------
extern "C" void kernel_launch(void* const* d_in, const int* in_sizes, int n_in,
                              void* d_out, int out_size, void* d_ws, size_t ws_size,
                              hipStream_t stream) {
    const float* x      = (const float*)d_in[0];
    const float* W_patch= (const float*)d_in[1];
    const float* b_patch= (const float*)d_in[2];
    const float* cls_tok= (const float*)d_in[3];
    const float* pos_emb= (const float*)d_in[4];
    const float* Wkl = (const float*)d_in[5];   const float* bkl = (const float*)d_in[6];
    const float* Wvl = (const float*)d_in[7];   const float* bvl = (const float*)d_in[8];
    const float* Wkr = (const float*)d_in[9];   const float* bkr = (const float*)d_in[10];
    const float* Wvr = (const float*)d_in[11];  const float* bvr = (const float*)d_in[12];
    const float* Wkt = (const float*)d_in[13];  const float* bkt = (const float*)d_in[14];
    const float* Wvt = (const float*)d_in[15];  const float* bvt = (const float*)d_in[16];
    const float* ln1_g = (const float*)d_in[17]; const float* ln1_b = (const float*)d_in[18];
    const float* Wqkv  = (const float*)d_in[19]; const float* bqkv  = (const float*)d_in[20];
    const float* Wo    = (const float*)d_in[21]; const float* bo    = (const float*)d_in[22];
    const float* ln2_g = (const float*)d_in[23]; const float* ln2_b = (const float*)d_in[24];
    const float* W1 = (const float*)d_in[25];   const float* b1 = (const float*)d_in[26];
    const float* W2 = (const float*)d_in[27];   const float* b2 = (const float*)d_in[28];
    const float* lnf_g = (const float*)d_in[29]; const float* lnf_b = (const float*)d_in[30];
    const float* W_head = (const float*)d_in[31]; const float* b_head = (const float*)d_in[32];

    // Workspace layout (bytes): total ~72.5 MB
    char* p = (char*)d_ws;
    float* h0 = (float*)p;                    p += (size_t)MP * 256 * 4;
    float* h1 = (float*)p;                    p += (size_t)MP * 256 * 4;
    unsigned short* qkb = (unsigned short*)p; p += (size_t)MP * 768 * 2;
    unsigned short* xnb = (unsigned short*)p; p += (size_t)MP * 256 * 2;
    unsigned short* ob  = (unsigned short*)p; p += (size_t)MP * 256 * 2;
    unsigned short* ff  = (unsigned short*)p; p += (size_t)MP * 3072 * 2;
    unsigned short* wb  = (unsigned short*)p;
    unsigned short* wqkv_b = wb;             // 196608
    unsigned short* wo_b   = wb + 196608;    // 65536
    unsigned short* w1_b   = wb + 262144;    // 786432
    unsigned short* w2_b   = wb + 1048576;   // 786432

    // rag scratch lives inside qkb (unused until the layer loop)
    float* ragws = (float*)qkb;
    float* M    = ragws;              // 32*256
    float* Ul   = ragws + 8192;
    float* Ur   = ragws + 2 * 8192;
    float* Ut   = ragws + 3 * 8192;
    float* cl   = ragws + 4 * 8192;   // 32
    float* cr   = cl + 32;
    float* ct   = cl + 64;
    float* fbuf = cl + 96;            // 30*256

    // ---- patch embedding as MFMA GEMM ----
    convert_kernel<<<64, 256, 0, stream>>>(W_patch, wqkv_b);   // Wp bf16 (wb free pre-loop)
    patchify_kernel<<<NPAT, 256, 0, stream>>>(x, xnb);
    cls_pos_kernel<<<Bz, 256, 0, stream>>>(cls_tok, pos_emb, h0);
    mfma_gemm64<3><<<dim3(4, NPAT / 128), 256, 0, stream>>>(
        xnb, 256, wqkv_b, 256, b_patch, h0, 256, 256, pos_emb);

    // ---- rag mixer (parallelized, fp32) ----
    means_kernel<<<Bz, 256, 0, stream>>>(h0, M);
    uvec_kernel<<<Bz, 256, 0, stream>>>(M, Wkl, bkl, Wkr, bkr, Wkt, bkt,
                                        Ul, Ur, Ut, cl, cr, ct);
    rag_score_kernel<<<(Bz - 2) * 4, 256, 0, stream>>>(
        h0, M, Ul, Ur, Ut, cl, cr, ct, Wvl, bvl, Wvr, bvr, Wvt, bvt, fbuf);
    rag_outer_kernel<<<(Bz - 2) * S, 256, 0, stream>>>(fbuf, M, h1);
    copy_edges<<<(2 * S * E + 255) / 256, 256, 0, stream>>>(h0, h1);

    const int gy = MP / 128;   // 50 M-tiles
    for (int l = 0; l < Ln; l++) {
        convert_w_kernel<<<1792, 256, 0, stream>>>(
            Wqkv + (size_t)l * 768 * 256, Wo + (size_t)l * 256 * 256,
            W1 + (size_t)l * Fd * 256, W2 + (size_t)l * 256 * Fd, wb);
        ln_kernel<<<MS / 4, 256, 0, stream>>>(h1, xnb, ln1_g + l * E, ln1_b + l * E);
        mfma_gemm<4><<<dim3(6, gy), 256, 0, stream>>>(
            xnb, 256, wqkv_b, 256, bqkv + l * 768, qkb, 768, 256);
        attn_kernel<<<Bz * Hn, 256, 0, stream>>>(qkb, ob);
        mfma_gemm64<1><<<dim3(4, gy), 256, 0, stream>>>(
            ob, 256, wo_b, 256, bo + l * 256, h1, 256, 256, nullptr);
        ln_kernel<<<MS / 4, 256, 0, stream>>>(h1, xnb, ln2_g + l * E, ln2_b + l * E);
        mfma_gemm<2><<<dim3(24, gy), 256, 0, stream>>>(
            xnb, 256, w1_b, 256, b1 + l * Fd, ff, 3072, 256);
        mfma_gemm64<1><<<dim3(4, gy), 256, 0, stream>>>(
            ff, 3072, w2_b, 3072, b2 + l * 256, h1, 256, 3072, nullptr);
    }
    head_kernel<<<Bz, 256, 0, stream>>>(h1, lnf_g, lnf_b, W_head, b_head, (float*)d_out);
}